// Round 1
// baseline (228.791 us; speedup 1.0000x reference)
//
#include <hip/hip_runtime.h>

#define BI 2
#define NPOS 2304
#define HIDC 256
#define NH 8
#define HDIM 32
#define ATT_SCALE 0.17677669529663687f  // 1/sqrt(32)

typedef __attribute__((ext_vector_type(8))) short short8;
typedef __attribute__((ext_vector_type(4))) short short4v;
typedef __attribute__((ext_vector_type(4))) float f32x4;
typedef __attribute__((ext_vector_type(4))) float float4v;

__device__ inline short f2bf(float f) {
  union { float f; unsigned u; } v; v.f = f;
  unsigned u = v.u;
  unsigned r = (u + 0x7FFFu + ((u >> 16) & 1u)) >> 16;
  return (short)r;
}

// ---------------------------------------------------------------------------
// Kernel 1: QKV projections.  out[c][n] = W[c][:] . X[:][n] + bias[c]
// z = b*6 + p ;  p 0..2 -> modal1 (K=256) Q1,K1,V1 ; p 3..5 -> modal2 (K=512)
// Q,K stored transposed per-head: [b*8+h][n][d] (bf16)
// V stored natural: [b][256][n] (bf16)
// ---------------------------------------------------------------------------
struct ProjArgs {
  const float* W[6];
  const float* bias[6];
  const float* X1;
  const float* X2;
  short* out[6];
};

__global__ __launch_bounds__(256) void proj_kernel(ProjArgs P) {
  const int nblk = blockIdx.x;   // 0..17
  const int mblk = blockIdx.y;   // 0..1
  const int z    = blockIdx.z;   // 0..11
  const int b = z / 6, p = z % 6;
  const int K = (p < 3) ? 256 : 512;
  const float* Wp = P.W[p];
  const float* bp = P.bias[p];
  const float* Xp = (p < 3) ? (P.X1 + (size_t)b * 256 * NPOS)
                            : (P.X2 + (size_t)b * 512 * NPOS);
  short* outp = P.out[p];
  const int vmode = (p % 3 == 2);

  __shared__ __attribute__((aligned(16))) short Wl[128][72];
  __shared__ __attribute__((aligned(16))) short Xl[128][72];

  const int tid = threadIdx.x;
  const int lane = tid & 63;
  const int w = tid >> 6;
  const int wm = w >> 1, wn = w & 1;
  const int m0 = mblk * 128, n0 = nblk * 128;

  f32x4 acc[4][4];
  for (int i = 0; i < 4; i++)
    for (int j = 0; j < 4; j++)
      acc[i][j] = (f32x4){0.f, 0.f, 0.f, 0.f};

  for (int kt = 0; kt < K; kt += 64) {
    // stage W tile [128][64] f32 -> bf16 LDS
    for (int idx = tid; idx < 128 * 16; idx += 256) {
      int row = idx >> 4, q = (idx & 15) * 4;
      const float4v wv = *(const float4v*)(Wp + (size_t)(m0 + row) * K + kt + q);
      short4v s;
      s[0] = f2bf(wv[0]); s[1] = f2bf(wv[1]); s[2] = f2bf(wv[2]); s[3] = f2bf(wv[3]);
      *(short4v*)&Wl[row][q] = s;
    }
    // stage X tile [64][128] f32 -> transposed bf16 LDS Xl[n][k]
    for (int idx = tid; idx < 2048; idx += 256) {
      int n = idx & 127, kq = (idx >> 7) * 4;
      const float* xb = Xp + (size_t)(kt + kq) * NPOS + n0 + n;
      short4v s;
      s[0] = f2bf(xb[0]);
      s[1] = f2bf(xb[NPOS]);
      s[2] = f2bf(xb[2 * NPOS]);
      s[3] = f2bf(xb[3 * NPOS]);
      *(short4v*)&Xl[n][kq] = s;
    }
    __syncthreads();
#pragma unroll
    for (int kk = 0; kk < 2; kk++) {
      short8 af[4], bfr[4];
#pragma unroll
      for (int f = 0; f < 4; f++)
        af[f] = *(const short8*)&Wl[wm * 64 + f * 16 + (lane & 15)][kk * 32 + (lane >> 4) * 8];
#pragma unroll
      for (int f = 0; f < 4; f++)
        bfr[f] = *(const short8*)&Xl[wn * 64 + f * 16 + (lane & 15)][kk * 32 + (lane >> 4) * 8];
#pragma unroll
      for (int i = 0; i < 4; i++)
#pragma unroll
        for (int j = 0; j < 4; j++)
          acc[i][j] = __builtin_amdgcn_mfma_f32_16x16x32_bf16(af[i], bfr[j], acc[i][j], 0, 0, 0);
    }
    __syncthreads();
  }

  float bv[4][4];
#pragma unroll
  for (int i = 0; i < 4; i++)
#pragma unroll
    for (int r = 0; r < 4; r++)
      bv[i][r] = bp[m0 + wm * 64 + i * 16 + (lane >> 4) * 4 + r];

  if (vmode) {
    short* op = outp + (size_t)b * HIDC * NPOS;
#pragma unroll
    for (int i = 0; i < 4; i++) {
      int mrow = m0 + wm * 64 + i * 16 + (lane >> 4) * 4;
#pragma unroll
      for (int j = 0; j < 4; j++) {
        int n = n0 + wn * 64 + j * 16 + (lane & 15);
#pragma unroll
        for (int r = 0; r < 4; r++)
          op[(size_t)(mrow + r) * NPOS + n] = f2bf(acc[i][j][r] + bv[i][r]);
      }
    }
  } else {
#pragma unroll
    for (int i = 0; i < 4; i++) {
      int c0 = m0 + wm * 64 + i * 16 + (lane >> 4) * 4;  // 4 consecutive channels, same head
      int h = c0 >> 5, d0 = c0 & 31;
      short* op = outp + (size_t)(b * NH + h) * NPOS * HDIM;
#pragma unroll
      for (int j = 0; j < 4; j++) {
        int n = n0 + wn * 64 + j * 16 + (lane & 15);
        short4v s;
#pragma unroll
        for (int r = 0; r < 4; r++) s[r] = f2bf(acc[i][j][r] + bv[i][r]);
        *(short4v*)&op[(size_t)n * HDIM + d0] = s;
      }
    }
  }
}

// ---------------------------------------------------------------------------
// Kernel 2: flash cross-attention.
// grid: (36 q-tiles, 8 heads, 4 = b*2+dir). 4 waves, each owns 16 q-rows.
// dir 0: Q1 x K2/V2 -> O1 ; dir 1: Q2 x K1/V1 -> O2
// ---------------------------------------------------------------------------
__global__ __launch_bounds__(256) void attn_kernel(
    const short* Q1t, const short* K1t, const short* V1,
    const short* Q2t, const short* K2t, const short* V2,
    short* O1, short* O2) {
  const int qt = blockIdx.x;
  const int h  = blockIdx.y;
  const int z  = blockIdx.z;
  const int b = z >> 1, dir = z & 1;

  const short* Qp = (dir ? Q2t : Q1t) + (size_t)(b * NH + h) * NPOS * HDIM;
  const short* Kp = (dir ? K1t : K2t) + (size_t)(b * NH + h) * NPOS * HDIM;
  const short* Vp = (dir ? V1 : V2) + (size_t)b * HIDC * NPOS + (size_t)h * HDIM * NPOS;
  short*       Op = (dir ? O2 : O1) + (size_t)b * HIDC * NPOS + (size_t)h * HDIM * NPOS;

  __shared__ __attribute__((aligned(16))) short Ktl[64][40];
  __shared__ __attribute__((aligned(16))) short Vl[32][72];
  __shared__ __attribute__((aligned(16))) short Pl[4][16][72];

  const int tid = threadIdx.x, lane = tid & 63, w = tid >> 6;
  const int q0 = qt * 64 + w * 16;

  const short8 qf = *(const short8*)(Qp + (size_t)(q0 + (lane & 15)) * HDIM + (lane >> 4) * 8);

  const f32x4 fz = {0.f, 0.f, 0.f, 0.f};
  f32x4 acco[2];
  acco[0] = fz; acco[1] = fz;
  float mrun[4], lrun[4];
#pragma unroll
  for (int r = 0; r < 4; r++) { mrun[r] = -INFINITY; lrun[r] = 0.f; }

  const int krow = tid >> 2, kc = (tid & 3) * 8;
  const int vrow = tid >> 3, vc = (tid & 7) * 8;

  for (int kt = 0; kt < NPOS; kt += 64) {
    *(short8*)&Ktl[krow][kc] = *(const short8*)(Kp + (size_t)(kt + krow) * HDIM + kc);
    *(short8*)&Vl[vrow][vc]  = *(const short8*)(Vp + (size_t)vrow * NPOS + kt + vc);
    __syncthreads();

    f32x4 s[4];
#pragma unroll
    for (int f = 0; f < 4; f++) {
      short8 kb = *(const short8*)&Ktl[f * 16 + (lane & 15)][(lane >> 4) * 8];
      s[f] = __builtin_amdgcn_mfma_f32_16x16x32_bf16(qf, kb, fz, 0, 0, 0);
    }

#pragma unroll
    for (int r = 0; r < 4; r++) {
      float mx = fmaxf(fmaxf(s[0][r], s[1][r]), fmaxf(s[2][r], s[3][r]));
      mx = fmaxf(mx, __shfl_xor(mx, 1));
      mx = fmaxf(mx, __shfl_xor(mx, 2));
      mx = fmaxf(mx, __shfl_xor(mx, 4));
      mx = fmaxf(mx, __shfl_xor(mx, 8));
      float newm = fmaxf(mrun[r], mx);
      float corr = __expf((mrun[r] - newm) * ATT_SCALE);
      float ps = 0.f;
#pragma unroll
      for (int f = 0; f < 4; f++) {
        float pv = __expf((s[f][r] - newm) * ATT_SCALE);
        s[f][r] = pv;
        ps += pv;
      }
      ps += __shfl_xor(ps, 1);
      ps += __shfl_xor(ps, 2);
      ps += __shfl_xor(ps, 4);
      ps += __shfl_xor(ps, 8);
      lrun[r] = lrun[r] * corr + ps;
      mrun[r] = newm;
      acco[0][r] *= corr;
      acco[1][r] *= corr;
    }

    // P -> per-wave LDS (re-fragment for PV A-operand)
#pragma unroll
    for (int r = 0; r < 4; r++) {
      int ql = (lane >> 4) * 4 + r;
#pragma unroll
      for (int f = 0; f < 4; f++)
        Pl[w][ql][f * 16 + (lane & 15)] = f2bf(s[f][r]);
    }

#pragma unroll
    for (int mc = 0; mc < 2; mc++) {
      short8 pa = *(const short8*)&Pl[w][lane & 15][mc * 32 + (lane >> 4) * 8];
#pragma unroll
      for (int dc = 0; dc < 2; dc++) {
        short8 vb = *(const short8*)&Vl[dc * 16 + (lane & 15)][mc * 32 + (lane >> 4) * 8];
        acco[dc] = __builtin_amdgcn_mfma_f32_16x16x32_bf16(pa, vb, acco[dc], 0, 0, 0);
      }
    }
    __syncthreads();
  }

#pragma unroll
  for (int dc = 0; dc < 2; dc++) {
    short4v s4;
#pragma unroll
    for (int r = 0; r < 4; r++) s4[r] = f2bf(acco[dc][r] / lrun[(unsigned)r]);
    *(short4v*)&Op[(size_t)(dc * 16 + (lane & 15)) * NPOS + q0 + (lane >> 4) * 4] = s4;
  }
}

// ---------------------------------------------------------------------------
// Kernel 3: output projections (X is bf16 [256][N], out f32 into d_out)
// z = b*2 + dir? -> use z: b = z>>1, dir = z&1
// ---------------------------------------------------------------------------
__global__ __launch_bounds__(256) void outproj_kernel(
    const float* Wo1, const float* bo1, const float* Wo2, const float* bo2,
    const short* O1, const short* O2, float* out) {
  const int nblk = blockIdx.x, mblk = blockIdx.y, z = blockIdx.z;
  const int b = z >> 1, dir = z & 1;
  const float* Wp = dir ? Wo2 : Wo1;
  const float* bp = dir ? bo2 : bo1;
  const short* Xp = (dir ? O2 : O1) + (size_t)b * HIDC * NPOS;
  float* op = out + (size_t)dir * BI * HIDC * NPOS + (size_t)b * HIDC * NPOS;
  const int K = 256;

  __shared__ __attribute__((aligned(16))) short Wl[128][72];
  __shared__ __attribute__((aligned(16))) short Xl[128][72];

  const int tid = threadIdx.x;
  const int lane = tid & 63;
  const int w = tid >> 6;
  const int wm = w >> 1, wn = w & 1;
  const int m0 = mblk * 128, n0 = nblk * 128;

  f32x4 acc[4][4];
  for (int i = 0; i < 4; i++)
    for (int j = 0; j < 4; j++)
      acc[i][j] = (f32x4){0.f, 0.f, 0.f, 0.f};

  for (int kt = 0; kt < K; kt += 64) {
    for (int idx = tid; idx < 128 * 16; idx += 256) {
      int row = idx >> 4, q = (idx & 15) * 4;
      const float4v wv = *(const float4v*)(Wp + (size_t)(m0 + row) * K + kt + q);
      short4v s;
      s[0] = f2bf(wv[0]); s[1] = f2bf(wv[1]); s[2] = f2bf(wv[2]); s[3] = f2bf(wv[3]);
      *(short4v*)&Wl[row][q] = s;
    }
    for (int idx = tid; idx < 2048; idx += 256) {
      int n = idx & 127, kq = (idx >> 7) * 4;
      const short* xb = Xp + (size_t)(kt + kq) * NPOS + n0 + n;
      short4v s;
      s[0] = xb[0]; s[1] = xb[NPOS]; s[2] = xb[2 * NPOS]; s[3] = xb[3 * NPOS];
      *(short4v*)&Xl[n][kq] = s;
    }
    __syncthreads();
#pragma unroll
    for (int kk = 0; kk < 2; kk++) {
      short8 af[4], bfr[4];
#pragma unroll
      for (int f = 0; f < 4; f++)
        af[f] = *(const short8*)&Wl[wm * 64 + f * 16 + (lane & 15)][kk * 32 + (lane >> 4) * 8];
#pragma unroll
      for (int f = 0; f < 4; f++)
        bfr[f] = *(const short8*)&Xl[wn * 64 + f * 16 + (lane & 15)][kk * 32 + (lane >> 4) * 8];
#pragma unroll
      for (int i = 0; i < 4; i++)
#pragma unroll
        for (int j = 0; j < 4; j++)
          acc[i][j] = __builtin_amdgcn_mfma_f32_16x16x32_bf16(af[i], bfr[j], acc[i][j], 0, 0, 0);
    }
    __syncthreads();
  }

#pragma unroll
  for (int i = 0; i < 4; i++) {
    int mrow = m0 + wm * 64 + i * 16 + (lane >> 4) * 4;
#pragma unroll
    for (int r = 0; r < 4; r++) {
      float bb = bp[mrow + r];
#pragma unroll
      for (int j = 0; j < 4; j++) {
        int n = n0 + wn * 64 + j * 16 + (lane & 15);
        op[(size_t)(mrow + r) * NPOS + n] = acc[i][j][r] + bb;
      }
    }
  }
}

// ---------------------------------------------------------------------------
extern "C" void kernel_launch(void* const* d_in, const int* in_sizes, int n_in,
                              void* d_out, int out_size, void* d_ws, size_t ws_size,
                              hipStream_t stream) {
  const float* m1 = (const float*)d_in[0];
  const float* m2 = (const float*)d_in[1];

  const size_t SZ = (size_t)BI * HIDC * NPOS;  // elements per bf16 buffer
  short* ws = (short*)d_ws;
  short* Q1t = ws + 0 * SZ;
  short* K1t = ws + 1 * SZ;
  short* V1  = ws + 2 * SZ;
  short* Q2t = ws + 3 * SZ;
  short* K2t = ws + 4 * SZ;
  short* V2  = ws + 5 * SZ;
  short* O1  = ws + 6 * SZ;
  short* O2  = ws + 7 * SZ;

  ProjArgs P;
  P.W[0] = (const float*)d_in[2];  P.bias[0] = (const float*)d_in[3];   // Wq1
  P.W[1] = (const float*)d_in[4];  P.bias[1] = (const float*)d_in[5];   // Wk1
  P.W[2] = (const float*)d_in[6];  P.bias[2] = (const float*)d_in[7];   // Wv1
  P.W[3] = (const float*)d_in[8];  P.bias[3] = (const float*)d_in[9];   // Wq2
  P.W[4] = (const float*)d_in[10]; P.bias[4] = (const float*)d_in[11];  // Wk2
  P.W[5] = (const float*)d_in[12]; P.bias[5] = (const float*)d_in[13];  // Wv2
  P.X1 = m1; P.X2 = m2;
  P.out[0] = Q1t; P.out[1] = K1t; P.out[2] = V1;
  P.out[3] = Q2t; P.out[4] = K2t; P.out[5] = V2;

  hipLaunchKernelGGL(proj_kernel, dim3(18, 2, 12), dim3(256), 0, stream, P);
  hipLaunchKernelGGL(attn_kernel, dim3(36, 8, 4), dim3(256), 0, stream,
                     Q1t, K1t, V1, Q2t, K2t, V2, O1, O2);
  hipLaunchKernelGGL(outproj_kernel, dim3(18, 2, 4), dim3(256), 0, stream,
                     (const float*)d_in[14], (const float*)d_in[15],
                     (const float*)d_in[16], (const float*)d_in[17],
                     O1, O2, (float*)d_out);
}

// Round 2
// 219.854 us; speedup vs baseline: 1.0407x; 1.0407x over previous
//
#include <hip/hip_runtime.h>
#include <hip/hip_bf16.h>

#define BI 2
#define NPOS 2304
#define HIDC 256
#define NH 8
#define HDIM 32
// scale folded into Wq/bq: S' = S_raw * SCALE * log2(e), so P = 2^(S' - m')
#define QSCALE (0.17677669529663687f * 1.4426950408889634f)

typedef __attribute__((ext_vector_type(8))) short short8;
typedef __attribute__((ext_vector_type(4))) short short4v;
typedef __attribute__((ext_vector_type(4))) float f32x4;
typedef __attribute__((ext_vector_type(4))) float float4v;
typedef __attribute__((ext_vector_type(2))) unsigned uint2v;

__device__ inline short f2bf(float f) {
  union { float f; unsigned u; } v; v.f = f;
  unsigned u = v.u;
  unsigned r = (u + 0x7FFFu + ((u >> 16) & 1u)) >> 16;
  return (short)r;
}

__device__ inline float exp2_asm(float x) {
  float r; asm("v_exp_f32 %0, %1" : "=v"(r) : "v"(x)); return r;
}

__device__ inline unsigned pkbf(float a, float b) {
  __hip_bfloat162 h = __float22bfloat162_rn(make_float2(a, b));
  union { __hip_bfloat162 h; unsigned u; } cv; cv.h = h;
  return cv.u;
}

// ---------------------------------------------------------------------------
// Kernel 1: QKV projections.  out[c][n] = W[c][:] . X[:][n] + bias[c]
// z = b*6 + p ;  p 0..2 -> modal1 (K=256) Q1,K1,V1 ; p 3..5 -> modal2 (K=512)
// Q,K stored transposed per-head: [b*8+h][n][d] (bf16); Wq/bq scaled by QSCALE
// V stored natural: [b][256][n] (bf16)
// ---------------------------------------------------------------------------
struct ProjArgs {
  const float* W[6];
  const float* bias[6];
  const float* X1;
  const float* X2;
  short* out[6];
};

__global__ __launch_bounds__(256) void proj_kernel(ProjArgs P) {
  const int nblk = blockIdx.x;   // 0..17
  const int mblk = blockIdx.y;   // 0..1
  const int z    = blockIdx.z;   // 0..11
  const int b = z / 6, p = z % 6;
  const int K = (p < 3) ? 256 : 512;
  const float* Wp = P.W[p];
  const float* bp = P.bias[p];
  const float* Xp = (p < 3) ? (P.X1 + (size_t)b * 256 * NPOS)
                            : (P.X2 + (size_t)b * 512 * NPOS);
  short* outp = P.out[p];
  const int vmode = (p % 3 == 2);
  const float wscale = (p == 0 || p == 3) ? (float)QSCALE : 1.0f;

  __shared__ __attribute__((aligned(16))) short Wl[128][72];
  __shared__ __attribute__((aligned(16))) short Xl[128][72];

  const int tid = threadIdx.x;
  const int lane = tid & 63;
  const int w = tid >> 6;
  const int wm = w >> 1, wn = w & 1;
  const int m0 = mblk * 128, n0 = nblk * 128;

  f32x4 acc[4][4];
  for (int i = 0; i < 4; i++)
    for (int j = 0; j < 4; j++)
      acc[i][j] = (f32x4){0.f, 0.f, 0.f, 0.f};

  for (int kt = 0; kt < K; kt += 64) {
    // stage W tile [128][64] f32 -> bf16 LDS (apply wscale)
    for (int idx = tid; idx < 128 * 16; idx += 256) {
      int row = idx >> 4, q = (idx & 15) * 4;
      const float4v wv = *(const float4v*)(Wp + (size_t)(m0 + row) * K + kt + q);
      short4v s;
      s[0] = f2bf(wv[0] * wscale); s[1] = f2bf(wv[1] * wscale);
      s[2] = f2bf(wv[2] * wscale); s[3] = f2bf(wv[3] * wscale);
      *(short4v*)&Wl[row][q] = s;
    }
    // stage X tile [64][128] f32 -> transposed bf16 LDS Xl[n][k]
    for (int idx = tid; idx < 2048; idx += 256) {
      int n = idx & 127, kq = (idx >> 7) * 4;
      const float* xb = Xp + (size_t)(kt + kq) * NPOS + n0 + n;
      short4v s;
      s[0] = f2bf(xb[0]);
      s[1] = f2bf(xb[NPOS]);
      s[2] = f2bf(xb[2 * NPOS]);
      s[3] = f2bf(xb[3 * NPOS]);
      *(short4v*)&Xl[n][kq] = s;
    }
    __syncthreads();
#pragma unroll
    for (int kk = 0; kk < 2; kk++) {
      short8 af[4], bfr[4];
#pragma unroll
      for (int f = 0; f < 4; f++)
        af[f] = *(const short8*)&Wl[wm * 64 + f * 16 + (lane & 15)][kk * 32 + (lane >> 4) * 8];
#pragma unroll
      for (int f = 0; f < 4; f++)
        bfr[f] = *(const short8*)&Xl[wn * 64 + f * 16 + (lane & 15)][kk * 32 + (lane >> 4) * 8];
#pragma unroll
      for (int i = 0; i < 4; i++)
#pragma unroll
        for (int j = 0; j < 4; j++)
          acc[i][j] = __builtin_amdgcn_mfma_f32_16x16x32_bf16(af[i], bfr[j], acc[i][j], 0, 0, 0);
    }
    __syncthreads();
  }

  float bv[4][4];
#pragma unroll
  for (int i = 0; i < 4; i++)
#pragma unroll
    for (int r = 0; r < 4; r++)
      bv[i][r] = bp[m0 + wm * 64 + i * 16 + (lane >> 4) * 4 + r] * wscale;

  if (vmode) {
    short* op = outp + (size_t)b * HIDC * NPOS;
#pragma unroll
    for (int i = 0; i < 4; i++) {
      int mrow = m0 + wm * 64 + i * 16 + (lane >> 4) * 4;
#pragma unroll
      for (int j = 0; j < 4; j++) {
        int n = n0 + wn * 64 + j * 16 + (lane & 15);
#pragma unroll
        for (int r = 0; r < 4; r++)
          op[(size_t)(mrow + r) * NPOS + n] = f2bf(acc[i][j][r] + bv[i][r]);
      }
    }
  } else {
#pragma unroll
    for (int i = 0; i < 4; i++) {
      int c0 = m0 + wm * 64 + i * 16 + (lane >> 4) * 4;  // 4 consecutive channels, same head
      int h = c0 >> 5, d0 = c0 & 31;
      short* op = outp + (size_t)(b * NH + h) * NPOS * HDIM;
#pragma unroll
      for (int j = 0; j < 4; j++) {
        int n = n0 + wn * 64 + j * 16 + (lane & 15);
        short4v s;
#pragma unroll
        for (int r = 0; r < 4; r++) s[r] = f2bf(acc[i][j][r] + bv[i][r]);
        *(short4v*)&op[(size_t)n * HDIM + d0] = s;
      }
    }
  }
}

// ---------------------------------------------------------------------------
// Kernel 2: flash cross-attention, swapped-QK^T structure.
// One wave per block, 16 queries per wave. Zero barriers; K/V frag-loaded
// straight from global (L2-resident: 294KB/head). Grid 4608, XCD-swizzled so
// each XCD owns 4 whole heads (1.2MB < 4MB L2).
// sT = mfma(K,Q): lane = (q=lane&15, g=lane>>4) holds S^T[key=f*16+g*4+r][q].
// PV: O^T[d][q] += mfma(V_nat frag, P frag) with P re-packed via per-wave LDS.
// ---------------------------------------------------------------------------
__global__ __launch_bounds__(64) void attn_kernel(
    const short* Q1t, const short* K1t, const short* V1,
    const short* Q2t, const short* K2t, const short* V2,
    short* O1, short* O2) {
  // bijective XCD swizzle: 4608 blocks = 8 XCDs x 576 (= 4 heads x 144 q-tiles)
  const int id = blockIdx.x;
  const int nid = (id & 7) * 576 + (id >> 3);
  const int wt = nid % 144;           // q-tile index (16 rows)
  const int rest = nid / 144;         // 0..31
  const int h = rest & 7;
  const int z = rest >> 3;            // 0..3
  const int b = z >> 1, dir = z & 1;

  const short* Qp = (dir ? Q2t : Q1t) + (size_t)(b * NH + h) * NPOS * HDIM;
  const short* Kp = (dir ? K1t : K2t) + (size_t)(b * NH + h) * NPOS * HDIM;
  const short* Vp = (dir ? V1 : V2) + (size_t)b * HIDC * NPOS + (size_t)h * HDIM * NPOS;
  short*       Op = (dir ? O2 : O1) + (size_t)b * HIDC * NPOS + (size_t)h * HDIM * NPOS;

  __shared__ __attribute__((aligned(16))) short Pl[16][68];

  const int lane = threadIdx.x;       // 0..63
  const int q = lane & 15, g = lane >> 4;
  const int q0 = wt * 16;

  // Q as B-frag (Q^T[n][d] layout: lane q reads 8 consecutive d at d0=g*8)
  const short8 qf = *(const short8*)(Qp + (size_t)(q0 + q) * HDIM + g * 8);

  const f32x4 fz = {0.f, 0.f, 0.f, 0.f};
  f32x4 acco0 = fz, acco1 = fz;       // O^T frags: rows d = g*4+r (+16)
  float mrun = -INFINITY, lrun = 0.f;

  short8 ka[4], kb[4];
#pragma unroll
  for (int f = 0; f < 4; f++)
    ka[f] = *(const short8*)(Kp + ((size_t)(f * 16 + q) << 5) + g * 8);

  auto body = [&](short8* kf, short8* kn, int kt, int ktn) {
    // prefetch next K tile's frags
#pragma unroll
    for (int f = 0; f < 4; f++)
      kn[f] = *(const short8*)(Kp + ((size_t)(ktn + f * 16 + q) << 5) + g * 8);
    // V frags for this tile (A-operand of O^T mfma; V natural [d][n])
    short8 vf[2][2];
#pragma unroll
    for (int dc = 0; dc < 2; dc++)
#pragma unroll
      for (int mc = 0; mc < 2; mc++)
        vf[dc][mc] = *(const short8*)(Vp + (size_t)(dc * 16 + q) * NPOS + kt + mc * 32 + g * 8);

    // S^T = K . Q^T  (4 frags cover 64 keys x 16 queries)
    f32x4 sT[4];
#pragma unroll
    for (int f = 0; f < 4; f++)
      sT[f] = __builtin_amdgcn_mfma_f32_16x16x32_bf16(kf[f], qf, fz, 0, 0, 0);

    // online softmax: lane-local over 16 keys, then xor16/xor32 across groups
    float mx = fmaxf(fmaxf(fmaxf(sT[0][0], sT[0][1]), fmaxf(sT[0][2], sT[0][3])),
                     fmaxf(fmaxf(sT[1][0], sT[1][1]), fmaxf(sT[1][2], sT[1][3])));
    float mx2 = fmaxf(fmaxf(fmaxf(sT[2][0], sT[2][1]), fmaxf(sT[2][2], sT[2][3])),
                      fmaxf(fmaxf(sT[3][0], sT[3][1]), fmaxf(sT[3][2], sT[3][3])));
    mx = fmaxf(mx, mx2);
    mx = fmaxf(mx, __shfl_xor(mx, 16));
    mx = fmaxf(mx, __shfl_xor(mx, 32));
    float newm = fmaxf(mrun, mx);
    float corr = exp2_asm(mrun - newm);
    float ps = 0.f;
#pragma unroll
    for (int f = 0; f < 4; f++)
#pragma unroll
      for (int r = 0; r < 4; r++) {
        float p = exp2_asm(sT[f][r] - newm);
        sT[f][r] = p;
        ps += p;
      }
    ps += __shfl_xor(ps, 16);
    ps += __shfl_xor(ps, 32);
    lrun = lrun * corr + ps;
    mrun = newm;
#pragma unroll
    for (int r = 0; r < 4; r++) { acco0[r] *= corr; acco1[r] *= corr; }

    // pack P -> per-wave LDS row q (keys consecutive per lane), re-read as B-frag
#pragma unroll
    for (int f = 0; f < 4; f++) {
      uint2v pk;
      pk[0] = pkbf(sT[f][0], sT[f][1]);
      pk[1] = pkbf(sT[f][2], sT[f][3]);
      *(uint2v*)&Pl[q][f * 16 + g * 4] = pk;
    }
    short8 pb0 = *(const short8*)&Pl[q][g * 8];
    short8 pb1 = *(const short8*)&Pl[q][32 + g * 8];
    acco0 = __builtin_amdgcn_mfma_f32_16x16x32_bf16(vf[0][0], pb0, acco0, 0, 0, 0);
    acco0 = __builtin_amdgcn_mfma_f32_16x16x32_bf16(vf[0][1], pb1, acco0, 0, 0, 0);
    acco1 = __builtin_amdgcn_mfma_f32_16x16x32_bf16(vf[1][0], pb0, acco1, 0, 0, 0);
    acco1 = __builtin_amdgcn_mfma_f32_16x16x32_bf16(vf[1][1], pb1, acco1, 0, 0, 0);
  };

  for (int kt = 0; kt < NPOS; kt += 128) {
    body(ka, kb, kt, kt + 64);
    body(kb, ka, kt + 64, (kt + 128 < NPOS) ? kt + 128 : 0);
  }

  const float rl = __builtin_amdgcn_rcpf(lrun);
#pragma unroll
  for (int r = 0; r < 4; r++) {
    Op[(size_t)(g * 4 + r) * NPOS + q0 + q] = f2bf(acco0[r] * rl);
    Op[(size_t)(16 + g * 4 + r) * NPOS + q0 + q] = f2bf(acco1[r] * rl);
  }
}

// ---------------------------------------------------------------------------
// Kernel 3: output projections (X is bf16 [256][N], out f32 into d_out)
// ---------------------------------------------------------------------------
__global__ __launch_bounds__(256) void outproj_kernel(
    const float* Wo1, const float* bo1, const float* Wo2, const float* bo2,
    const short* O1, const short* O2, float* out) {
  const int nblk = blockIdx.x, mblk = blockIdx.y, z = blockIdx.z;
  const int b = z >> 1, dir = z & 1;
  const float* Wp = dir ? Wo2 : Wo1;
  const float* bp = dir ? bo2 : bo1;
  const short* Xp = (dir ? O2 : O1) + (size_t)b * HIDC * NPOS;
  float* op = out + (size_t)dir * BI * HIDC * NPOS + (size_t)b * HIDC * NPOS;
  const int K = 256;

  __shared__ __attribute__((aligned(16))) short Wl[128][72];
  __shared__ __attribute__((aligned(16))) short Xl[128][72];

  const int tid = threadIdx.x;
  const int lane = tid & 63;
  const int w = tid >> 6;
  const int wm = w >> 1, wn = w & 1;
  const int m0 = mblk * 128, n0 = nblk * 128;

  f32x4 acc[4][4];
  for (int i = 0; i < 4; i++)
    for (int j = 0; j < 4; j++)
      acc[i][j] = (f32x4){0.f, 0.f, 0.f, 0.f};

  for (int kt = 0; kt < K; kt += 64) {
    for (int idx = tid; idx < 128 * 16; idx += 256) {
      int row = idx >> 4, q = (idx & 15) * 4;
      const float4v wv = *(const float4v*)(Wp + (size_t)(m0 + row) * K + kt + q);
      short4v s;
      s[0] = f2bf(wv[0]); s[1] = f2bf(wv[1]); s[2] = f2bf(wv[2]); s[3] = f2bf(wv[3]);
      *(short4v*)&Wl[row][q] = s;
    }
    for (int idx = tid; idx < 2048; idx += 256) {
      int n = idx & 127, kq = (idx >> 7) * 4;
      const short* xb = Xp + (size_t)(kt + kq) * NPOS + n0 + n;
      short4v s;
      s[0] = xb[0]; s[1] = xb[NPOS]; s[2] = xb[2 * NPOS]; s[3] = xb[3 * NPOS];
      *(short4v*)&Xl[n][kq] = s;
    }
    __syncthreads();
#pragma unroll
    for (int kk = 0; kk < 2; kk++) {
      short8 af[4], bfr[4];
#pragma unroll
      for (int f = 0; f < 4; f++)
        af[f] = *(const short8*)&Wl[wm * 64 + f * 16 + (lane & 15)][kk * 32 + (lane >> 4) * 8];
#pragma unroll
      for (int f = 0; f < 4; f++)
        bfr[f] = *(const short8*)&Xl[wn * 64 + f * 16 + (lane & 15)][kk * 32 + (lane >> 4) * 8];
#pragma unroll
      for (int i = 0; i < 4; i++)
#pragma unroll
        for (int j = 0; j < 4; j++)
          acc[i][j] = __builtin_amdgcn_mfma_f32_16x16x32_bf16(af[i], bfr[j], acc[i][j], 0, 0, 0);
    }
    __syncthreads();
  }

#pragma unroll
  for (int i = 0; i < 4; i++) {
    int mrow = m0 + wm * 64 + i * 16 + (lane >> 4) * 4;
#pragma unroll
    for (int r = 0; r < 4; r++) {
      float bb = bp[mrow + r];
#pragma unroll
      for (int j = 0; j < 4; j++) {
        int n = n0 + wn * 64 + j * 16 + (lane & 15);
        op[(size_t)(mrow + r) * NPOS + n] = acc[i][j][r] + bb;
      }
    }
  }
}

// ---------------------------------------------------------------------------
extern "C" void kernel_launch(void* const* d_in, const int* in_sizes, int n_in,
                              void* d_out, int out_size, void* d_ws, size_t ws_size,
                              hipStream_t stream) {
  const float* m1 = (const float*)d_in[0];
  const float* m2 = (const float*)d_in[1];

  const size_t SZ = (size_t)BI * HIDC * NPOS;  // elements per bf16 buffer
  short* ws = (short*)d_ws;
  short* Q1t = ws + 0 * SZ;
  short* K1t = ws + 1 * SZ;
  short* V1  = ws + 2 * SZ;
  short* Q2t = ws + 3 * SZ;
  short* K2t = ws + 4 * SZ;
  short* V2  = ws + 5 * SZ;
  short* O1  = ws + 6 * SZ;
  short* O2  = ws + 7 * SZ;

  ProjArgs P;
  P.W[0] = (const float*)d_in[2];  P.bias[0] = (const float*)d_in[3];   // Wq1 (scaled)
  P.W[1] = (const float*)d_in[4];  P.bias[1] = (const float*)d_in[5];   // Wk1
  P.W[2] = (const float*)d_in[6];  P.bias[2] = (const float*)d_in[7];   // Wv1
  P.W[3] = (const float*)d_in[8];  P.bias[3] = (const float*)d_in[9];   // Wq2 (scaled)
  P.W[4] = (const float*)d_in[10]; P.bias[4] = (const float*)d_in[11];  // Wk2
  P.W[5] = (const float*)d_in[12]; P.bias[5] = (const float*)d_in[13];  // Wv2
  P.X1 = m1; P.X2 = m2;
  P.out[0] = Q1t; P.out[1] = K1t; P.out[2] = V1;
  P.out[3] = Q2t; P.out[4] = K2t; P.out[5] = V2;

  hipLaunchKernelGGL(proj_kernel, dim3(18, 2, 12), dim3(256), 0, stream, P);
  hipLaunchKernelGGL(attn_kernel, dim3(4608), dim3(64), 0, stream,
                     Q1t, K1t, V1, Q2t, K2t, V2, O1, O2);
  hipLaunchKernelGGL(outproj_kernel, dim3(18, 2, 4), dim3(256), 0, stream,
                     (const float*)d_in[14], (const float*)d_in[15],
                     (const float*)d_in[16], (const float*)d_in[17],
                     O1, O2, (float*)d_out);
}

// Round 3
// 207.572 us; speedup vs baseline: 1.1022x; 1.0592x over previous
//
#include <hip/hip_runtime.h>
#include <hip/hip_bf16.h>

#define BI 2
#define NPOS 2304
#define HIDC 256
#define NH 8
#define HDIM 32
// scale folded into Wq/bq: S' = S_raw * SCALE * log2(e), so P = 2^(S' - 32)
#define QSCALE (0.17677669529663687f * 1.4426950408889634f)

typedef __attribute__((ext_vector_type(8))) short short8;
typedef __attribute__((ext_vector_type(4))) short short4v;
typedef __attribute__((ext_vector_type(4))) float f32x4;
typedef __attribute__((ext_vector_type(4))) float float4v;
typedef __attribute__((ext_vector_type(2))) unsigned uint2v;

__device__ inline short f2bf(float f) {
  union { float f; unsigned u; } v; v.f = f;
  unsigned u = v.u;
  unsigned r = (u + 0x7FFFu + ((u >> 16) & 1u)) >> 16;
  return (short)r;
}

__device__ inline float exp2_asm(float x) {
  float r; asm("v_exp_f32 %0, %1" : "=v"(r) : "v"(x)); return r;
}

__device__ inline unsigned pkbf(float a, float b) {
  __hip_bfloat162 h = __float22bfloat162_rn(make_float2(a, b));
  union { __hip_bfloat162 h; unsigned u; } cv; cv.h = h;
  return cv.u;
}

// ---------------------------------------------------------------------------
// Kernel 1: QKV projections (unchanged from round 2).
// ---------------------------------------------------------------------------
struct ProjArgs {
  const float* W[6];
  const float* bias[6];
  const float* X1;
  const float* X2;
  short* out[6];
};

__global__ __launch_bounds__(256) void proj_kernel(ProjArgs P) {
  const int nblk = blockIdx.x;   // 0..17
  const int mblk = blockIdx.y;   // 0..1
  const int z    = blockIdx.z;   // 0..11
  const int b = z / 6, p = z % 6;
  const int K = (p < 3) ? 256 : 512;
  const float* Wp = P.W[p];
  const float* bp = P.bias[p];
  const float* Xp = (p < 3) ? (P.X1 + (size_t)b * 256 * NPOS)
                            : (P.X2 + (size_t)b * 512 * NPOS);
  short* outp = P.out[p];
  const int vmode = (p % 3 == 2);
  const float wscale = (p == 0 || p == 3) ? (float)QSCALE : 1.0f;

  __shared__ __attribute__((aligned(16))) short Wl[128][72];
  __shared__ __attribute__((aligned(16))) short Xl[128][72];

  const int tid = threadIdx.x;
  const int lane = tid & 63;
  const int w = tid >> 6;
  const int wm = w >> 1, wn = w & 1;
  const int m0 = mblk * 128, n0 = nblk * 128;

  f32x4 acc[4][4];
  for (int i = 0; i < 4; i++)
    for (int j = 0; j < 4; j++)
      acc[i][j] = (f32x4){0.f, 0.f, 0.f, 0.f};

  for (int kt = 0; kt < K; kt += 64) {
    for (int idx = tid; idx < 128 * 16; idx += 256) {
      int row = idx >> 4, q = (idx & 15) * 4;
      const float4v wv = *(const float4v*)(Wp + (size_t)(m0 + row) * K + kt + q);
      short4v s;
      s[0] = f2bf(wv[0] * wscale); s[1] = f2bf(wv[1] * wscale);
      s[2] = f2bf(wv[2] * wscale); s[3] = f2bf(wv[3] * wscale);
      *(short4v*)&Wl[row][q] = s;
    }
    for (int idx = tid; idx < 2048; idx += 256) {
      int n = idx & 127, kq = (idx >> 7) * 4;
      const float* xb = Xp + (size_t)(kt + kq) * NPOS + n0 + n;
      short4v s;
      s[0] = f2bf(xb[0]);
      s[1] = f2bf(xb[NPOS]);
      s[2] = f2bf(xb[2 * NPOS]);
      s[3] = f2bf(xb[3 * NPOS]);
      *(short4v*)&Xl[n][kq] = s;
    }
    __syncthreads();
#pragma unroll
    for (int kk = 0; kk < 2; kk++) {
      short8 af[4], bfr[4];
#pragma unroll
      for (int f = 0; f < 4; f++)
        af[f] = *(const short8*)&Wl[wm * 64 + f * 16 + (lane & 15)][kk * 32 + (lane >> 4) * 8];
#pragma unroll
      for (int f = 0; f < 4; f++)
        bfr[f] = *(const short8*)&Xl[wn * 64 + f * 16 + (lane & 15)][kk * 32 + (lane >> 4) * 8];
#pragma unroll
      for (int i = 0; i < 4; i++)
#pragma unroll
        for (int j = 0; j < 4; j++)
          acc[i][j] = __builtin_amdgcn_mfma_f32_16x16x32_bf16(af[i], bfr[j], acc[i][j], 0, 0, 0);
    }
    __syncthreads();
  }

  float bv[4][4];
#pragma unroll
  for (int i = 0; i < 4; i++)
#pragma unroll
    for (int r = 0; r < 4; r++)
      bv[i][r] = bp[m0 + wm * 64 + i * 16 + (lane >> 4) * 4 + r] * wscale;

  if (vmode) {
    short* op = outp + (size_t)b * HIDC * NPOS;
#pragma unroll
    for (int i = 0; i < 4; i++) {
      int mrow = m0 + wm * 64 + i * 16 + (lane >> 4) * 4;
#pragma unroll
      for (int j = 0; j < 4; j++) {
        int n = n0 + wn * 64 + j * 16 + (lane & 15);
#pragma unroll
        for (int r = 0; r < 4; r++)
          op[(size_t)(mrow + r) * NPOS + n] = f2bf(acc[i][j][r] + bv[i][r]);
      }
    }
  } else {
#pragma unroll
    for (int i = 0; i < 4; i++) {
      int c0 = m0 + wm * 64 + i * 16 + (lane >> 4) * 4;
      int h = c0 >> 5, d0 = c0 & 31;
      short* op = outp + (size_t)(b * NH + h) * NPOS * HDIM;
#pragma unroll
      for (int j = 0; j < 4; j++) {
        int n = n0 + wn * 64 + j * 16 + (lane & 15);
        short4v s;
#pragma unroll
        for (int r = 0; r < 4; r++) s[r] = f2bf(acc[i][j][r] + bv[i][r]);
        *(short4v*)&op[(size_t)n * HDIM + d0] = s;
      }
    }
  }
}

// ---------------------------------------------------------------------------
// Kernel 2: flash cross-attention, fixed-max (no online softmax), 2-way K-split.
// Block = 2 waves; wave w handles keys [w*1152, w*1152+1152). 16 queries/block.
// P = 2^(S' - 32): scale cancels in O/l; no max tracking, no in-loop shuffles.
// Partials combine by plain addition via one end-of-kernel LDS merge.
// ---------------------------------------------------------------------------
__global__ __launch_bounds__(128) void attn_kernel(
    const short* Q1t, const short* K1t, const short* V1,
    const short* Q2t, const short* K2t, const short* V2,
    short* O1, short* O2) {
  // bijective XCD swizzle: 4608 blocks = 8 XCDs x 576 (= 4 (z,h) combos x 144)
  const int id = blockIdx.x;
  const int nid = (id & 7) * 576 + (id >> 3);
  const int wt = nid % 144;           // q-tile index (16 rows)
  const int rest = nid / 144;         // 0..31
  const int h = rest & 7;
  const int z = rest >> 3;            // 0..3
  const int b = z >> 1, dir = z & 1;

  const short* Qp = (dir ? Q2t : Q1t) + (size_t)(b * NH + h) * NPOS * HDIM;
  const short* Kp = (dir ? K1t : K2t) + (size_t)(b * NH + h) * NPOS * HDIM;
  const short* Vp = (dir ? V1 : V2) + (size_t)b * HIDC * NPOS + (size_t)h * HDIM * NPOS;
  short*       Op = (dir ? O2 : O1) + (size_t)b * HIDC * NPOS + (size_t)h * HDIM * NPOS;

  // P scratch, one 16x128 bf16 tile per wave, pitch 256B, XOR-swizzled
  __shared__ __attribute__((aligned(16))) short Pl[2][16][128];

  const int tid = threadIdx.x;
  const int wid = tid >> 6;
  const int lane = tid & 63;
  const int q = lane & 15, g = lane >> 4;
  const int q0 = wt * 16;
  const int k0 = wid * 1152;

  const short8 qf = *(const short8*)(Qp + (size_t)(q0 + q) * HDIM + g * 8);
  const short* Kw = Kp + (size_t)k0 * HDIM;

  const f32x4 fz = {0.f, 0.f, 0.f, 0.f};
  f32x4 acco0 = fz, acco1 = fz;       // O^T partial: rows d = g*4+r (+16), col q
  f32x4 lrv = fz;                     // lane-local partial l sums (per r, summed later)

  const int swz = (q & 7) << 4;
  char* prow = (char*)&Pl[wid][q][0];

  short8 ka[4], kb[4];
#pragma unroll
  for (int f = 0; f < 4; f++)
    ka[f] = *(const short8*)(Kw + ((size_t)(f * 16 + q) << 5) + g * 8);

  auto body = [&](short8* kf, short8* kn, int kt, int ktn) {
    // prefetch next K tile's frags (double buffer)
#pragma unroll
    for (int f = 0; f < 4; f++)
      kn[f] = *(const short8*)(Kw + ((size_t)(ktn + f * 16 + q) << 5) + g * 8);
    // V frags for this tile (used ~300cyc later, after exp+pack)
    short8 vf[2][2];
#pragma unroll
    for (int dc = 0; dc < 2; dc++)
#pragma unroll
      for (int mc = 0; mc < 2; mc++)
        vf[dc][mc] = *(const short8*)(Vp + (size_t)(dc * 16 + q) * NPOS + k0 + kt + mc * 32 + g * 8);

    // S^T = K . Q^T
    f32x4 sT[4];
#pragma unroll
    for (int f = 0; f < 4; f++)
      sT[f] = __builtin_amdgcn_mfma_f32_16x16x32_bf16(kf[f], qf, fz, 0, 0, 0);

    // fixed-max exponential; lane-local l accumulation (4 independent chains)
#pragma unroll
    for (int f = 0; f < 4; f++)
#pragma unroll
      for (int r = 0; r < 4; r++) {
        float p = exp2_asm(sT[f][r] - 32.0f);
        sT[f][r] = p;
        lrv[r] += p;
      }

    // pack P -> swizzled LDS row q, re-read as PV B-frags
#pragma unroll
    for (int f = 0; f < 4; f++) {
      uint2v pk;
      pk[0] = pkbf(sT[f][0], sT[f][1]);
      pk[1] = pkbf(sT[f][2], sT[f][3]);
      *(uint2v*)(prow + ((f * 32 + g * 8) ^ swz)) = pk;
    }
    short8 pb0 = *(const short8*)(prow + ((g * 16) ^ swz));
    short8 pb1 = *(const short8*)(prow + ((64 + g * 16) ^ swz));
    acco0 = __builtin_amdgcn_mfma_f32_16x16x32_bf16(vf[0][0], pb0, acco0, 0, 0, 0);
    acco0 = __builtin_amdgcn_mfma_f32_16x16x32_bf16(vf[0][1], pb1, acco0, 0, 0, 0);
    acco1 = __builtin_amdgcn_mfma_f32_16x16x32_bf16(vf[1][0], pb0, acco1, 0, 0, 0);
    acco1 = __builtin_amdgcn_mfma_f32_16x16x32_bf16(vf[1][1], pb1, acco1, 0, 0, 0);
  };

  for (int kt = 0; kt < 1152; kt += 128) {
    body(ka, kb, kt, kt + 64);
    body(kb, ka, kt + 64, (kt + 128 < 1152) ? kt + 128 : 0);
  }

  float lrun = lrv[0] + lrv[1] + lrv[2] + lrv[3];
  lrun += __shfl_xor(lrun, 16);
  lrun += __shfl_xor(lrun, 32);

  // cross-wave merge: wave 1 dumps partials into its Pl region; wave 0 combines
  float* mb = (float*)&Pl[1][0][0];
  if (wid == 1) {
#pragma unroll
    for (int r = 0; r < 4; r++) {
      mb[lane * 12 + r] = acco0[r];
      mb[lane * 12 + 4 + r] = acco1[r];
    }
    mb[lane * 12 + 8] = lrun;
  }
  __syncthreads();
  if (wid == 0) {
#pragma unroll
    for (int r = 0; r < 4; r++) {
      acco0[r] += mb[lane * 12 + r];
      acco1[r] += mb[lane * 12 + 4 + r];
    }
    lrun += mb[lane * 12 + 8];
    const float rl = 1.0f / lrun;
#pragma unroll
    for (int r = 0; r < 4; r++) {
      Op[(size_t)(g * 4 + r) * NPOS + q0 + q] = f2bf(acco0[r] * rl);
      Op[(size_t)(16 + g * 4 + r) * NPOS + q0 + q] = f2bf(acco1[r] * rl);
    }
  }
}

// ---------------------------------------------------------------------------
// Kernel 3: output projections (unchanged from round 2).
// ---------------------------------------------------------------------------
__global__ __launch_bounds__(256) void outproj_kernel(
    const float* Wo1, const float* bo1, const float* Wo2, const float* bo2,
    const short* O1, const short* O2, float* out) {
  const int nblk = blockIdx.x, mblk = blockIdx.y, z = blockIdx.z;
  const int b = z >> 1, dir = z & 1;
  const float* Wp = dir ? Wo2 : Wo1;
  const float* bp = dir ? bo2 : bo1;
  const short* Xp = (dir ? O2 : O1) + (size_t)b * HIDC * NPOS;
  float* op = out + (size_t)dir * BI * HIDC * NPOS + (size_t)b * HIDC * NPOS;
  const int K = 256;

  __shared__ __attribute__((aligned(16))) short Wl[128][72];
  __shared__ __attribute__((aligned(16))) short Xl[128][72];

  const int tid = threadIdx.x;
  const int lane = tid & 63;
  const int w = tid >> 6;
  const int wm = w >> 1, wn = w & 1;
  const int m0 = mblk * 128, n0 = nblk * 128;

  f32x4 acc[4][4];
  for (int i = 0; i < 4; i++)
    for (int j = 0; j < 4; j++)
      acc[i][j] = (f32x4){0.f, 0.f, 0.f, 0.f};

  for (int kt = 0; kt < K; kt += 64) {
    for (int idx = tid; idx < 128 * 16; idx += 256) {
      int row = idx >> 4, q = (idx & 15) * 4;
      const float4v wv = *(const float4v*)(Wp + (size_t)(m0 + row) * K + kt + q);
      short4v s;
      s[0] = f2bf(wv[0]); s[1] = f2bf(wv[1]); s[2] = f2bf(wv[2]); s[3] = f2bf(wv[3]);
      *(short4v*)&Wl[row][q] = s;
    }
    for (int idx = tid; idx < 2048; idx += 256) {
      int n = idx & 127, kq = (idx >> 7) * 4;
      const short* xb = Xp + (size_t)(kt + kq) * NPOS + n0 + n;
      short4v s;
      s[0] = xb[0]; s[1] = xb[NPOS]; s[2] = xb[2 * NPOS]; s[3] = xb[3 * NPOS];
      *(short4v*)&Xl[n][kq] = s;
    }
    __syncthreads();
#pragma unroll
    for (int kk = 0; kk < 2; kk++) {
      short8 af[4], bfr[4];
#pragma unroll
      for (int f = 0; f < 4; f++)
        af[f] = *(const short8*)&Wl[wm * 64 + f * 16 + (lane & 15)][kk * 32 + (lane >> 4) * 8];
#pragma unroll
      for (int f = 0; f < 4; f++)
        bfr[f] = *(const short8*)&Xl[wn * 64 + f * 16 + (lane & 15)][kk * 32 + (lane >> 4) * 8];
#pragma unroll
      for (int i = 0; i < 4; i++)
#pragma unroll
        for (int j = 0; j < 4; j++)
          acc[i][j] = __builtin_amdgcn_mfma_f32_16x16x32_bf16(af[i], bfr[j], acc[i][j], 0, 0, 0);
    }
    __syncthreads();
  }

#pragma unroll
  for (int i = 0; i < 4; i++) {
    int mrow = m0 + wm * 64 + i * 16 + (lane >> 4) * 4;
#pragma unroll
    for (int r = 0; r < 4; r++) {
      float bb = bp[mrow + r];
#pragma unroll
      for (int j = 0; j < 4; j++) {
        int n = n0 + wn * 64 + j * 16 + (lane & 15);
        op[(size_t)(mrow + r) * NPOS + n] = acc[i][j][r] + bb;
      }
    }
  }
}

// ---------------------------------------------------------------------------
extern "C" void kernel_launch(void* const* d_in, const int* in_sizes, int n_in,
                              void* d_out, int out_size, void* d_ws, size_t ws_size,
                              hipStream_t stream) {
  const float* m1 = (const float*)d_in[0];
  const float* m2 = (const float*)d_in[1];

  const size_t SZ = (size_t)BI * HIDC * NPOS;
  short* ws = (short*)d_ws;
  short* Q1t = ws + 0 * SZ;
  short* K1t = ws + 1 * SZ;
  short* V1  = ws + 2 * SZ;
  short* Q2t = ws + 3 * SZ;
  short* K2t = ws + 4 * SZ;
  short* V2  = ws + 5 * SZ;
  short* O1  = ws + 6 * SZ;
  short* O2  = ws + 7 * SZ;

  ProjArgs P;
  P.W[0] = (const float*)d_in[2];  P.bias[0] = (const float*)d_in[3];
  P.W[1] = (const float*)d_in[4];  P.bias[1] = (const float*)d_in[5];
  P.W[2] = (const float*)d_in[6];  P.bias[2] = (const float*)d_in[7];
  P.W[3] = (const float*)d_in[8];  P.bias[3] = (const float*)d_in[9];
  P.W[4] = (const float*)d_in[10]; P.bias[4] = (const float*)d_in[11];
  P.W[5] = (const float*)d_in[12]; P.bias[5] = (const float*)d_in[13];
  P.X1 = m1; P.X2 = m2;
  P.out[0] = Q1t; P.out[1] = K1t; P.out[2] = V1;
  P.out[3] = Q2t; P.out[4] = K2t; P.out[5] = V2;

  hipLaunchKernelGGL(proj_kernel, dim3(18, 2, 12), dim3(256), 0, stream, P);
  hipLaunchKernelGGL(attn_kernel, dim3(4608), dim3(128), 0, stream,
                     Q1t, K1t, V1, Q2t, K2t, V2, O1, O2);
  hipLaunchKernelGGL(outproj_kernel, dim3(18, 2, 4), dim3(256), 0, stream,
                     (const float*)d_in[14], (const float*)d_in[15],
                     (const float*)d_in[16], (const float*)d_in[17],
                     O1, O2, (float*)d_out);
}

// Round 4
// 142.901 us; speedup vs baseline: 1.6010x; 1.4526x over previous
//
#include <hip/hip_runtime.h>
#include <hip/hip_bf16.h>

#define BI 2
#define NPOS 2304
#define HIDC 256
#define NH 8
#define HDIM 32
// scale folded into Wq/bq: S' = S_raw * SCALE * log2(e), so P = 2^(S' - 32)
#define QSCALE (0.17677669529663687f * 1.4426950408889634f)

typedef __attribute__((ext_vector_type(8))) short short8;
typedef __attribute__((ext_vector_type(4))) short short4v;
typedef __attribute__((ext_vector_type(4))) float f32x4;
typedef __attribute__((ext_vector_type(4))) float float4v;
typedef __attribute__((ext_vector_type(2))) unsigned uint2v;

__device__ inline short f2bf(float f) {
  union { float f; unsigned u; } v; v.f = f;
  unsigned u = v.u;
  unsigned r = (u + 0x7FFFu + ((u >> 16) & 1u)) >> 16;
  return (short)r;
}

__device__ inline float exp2_asm(float x) {
  float r; asm("v_exp_f32 %0, %1" : "=v"(r) : "v"(x)); return r;
}

__device__ inline unsigned pkbf(float a, float b) {
  __hip_bfloat162 h = __float22bfloat162_rn(make_float2(a, b));
  union { __hip_bfloat162 h; unsigned u; } cv; cv.h = h;
  return cv.u;
}

// ---------------------------------------------------------------------------
// Kernel 1: QKV projections (unchanged from round 3).
// ---------------------------------------------------------------------------
struct ProjArgs {
  const float* W[6];
  const float* bias[6];
  const float* X1;
  const float* X2;
  short* out[6];
};

__global__ __launch_bounds__(256) void proj_kernel(ProjArgs P) {
  const int nblk = blockIdx.x;   // 0..17
  const int mblk = blockIdx.y;   // 0..1
  const int z    = blockIdx.z;   // 0..11
  const int b = z / 6, p = z % 6;
  const int K = (p < 3) ? 256 : 512;
  const float* Wp = P.W[p];
  const float* bp = P.bias[p];
  const float* Xp = (p < 3) ? (P.X1 + (size_t)b * 256 * NPOS)
                            : (P.X2 + (size_t)b * 512 * NPOS);
  short* outp = P.out[p];
  const int vmode = (p % 3 == 2);
  const float wscale = (p == 0 || p == 3) ? (float)QSCALE : 1.0f;

  __shared__ __attribute__((aligned(16))) short Wl[128][72];
  __shared__ __attribute__((aligned(16))) short Xl[128][72];

  const int tid = threadIdx.x;
  const int lane = tid & 63;
  const int w = tid >> 6;
  const int wm = w >> 1, wn = w & 1;
  const int m0 = mblk * 128, n0 = nblk * 128;

  f32x4 acc[4][4];
  for (int i = 0; i < 4; i++)
    for (int j = 0; j < 4; j++)
      acc[i][j] = (f32x4){0.f, 0.f, 0.f, 0.f};

  for (int kt = 0; kt < K; kt += 64) {
    for (int idx = tid; idx < 128 * 16; idx += 256) {
      int row = idx >> 4, q = (idx & 15) * 4;
      const float4v wv = *(const float4v*)(Wp + (size_t)(m0 + row) * K + kt + q);
      short4v s;
      s[0] = f2bf(wv[0] * wscale); s[1] = f2bf(wv[1] * wscale);
      s[2] = f2bf(wv[2] * wscale); s[3] = f2bf(wv[3] * wscale);
      *(short4v*)&Wl[row][q] = s;
    }
    for (int idx = tid; idx < 2048; idx += 256) {
      int n = idx & 127, kq = (idx >> 7) * 4;
      const float* xb = Xp + (size_t)(kt + kq) * NPOS + n0 + n;
      short4v s;
      s[0] = f2bf(xb[0]);
      s[1] = f2bf(xb[NPOS]);
      s[2] = f2bf(xb[2 * NPOS]);
      s[3] = f2bf(xb[3 * NPOS]);
      *(short4v*)&Xl[n][kq] = s;
    }
    __syncthreads();
#pragma unroll
    for (int kk = 0; kk < 2; kk++) {
      short8 af[4], bfr[4];
#pragma unroll
      for (int f = 0; f < 4; f++)
        af[f] = *(const short8*)&Wl[wm * 64 + f * 16 + (lane & 15)][kk * 32 + (lane >> 4) * 8];
#pragma unroll
      for (int f = 0; f < 4; f++)
        bfr[f] = *(const short8*)&Xl[wn * 64 + f * 16 + (lane & 15)][kk * 32 + (lane >> 4) * 8];
#pragma unroll
      for (int i = 0; i < 4; i++)
#pragma unroll
        for (int j = 0; j < 4; j++)
          acc[i][j] = __builtin_amdgcn_mfma_f32_16x16x32_bf16(af[i], bfr[j], acc[i][j], 0, 0, 0);
    }
    __syncthreads();
  }

  float bv[4][4];
#pragma unroll
  for (int i = 0; i < 4; i++)
#pragma unroll
    for (int r = 0; r < 4; r++)
      bv[i][r] = bp[m0 + wm * 64 + i * 16 + (lane >> 4) * 4 + r] * wscale;

  if (vmode) {
    short* op = outp + (size_t)b * HIDC * NPOS;
#pragma unroll
    for (int i = 0; i < 4; i++) {
      int mrow = m0 + wm * 64 + i * 16 + (lane >> 4) * 4;
#pragma unroll
      for (int j = 0; j < 4; j++) {
        int n = n0 + wn * 64 + j * 16 + (lane & 15);
#pragma unroll
        for (int r = 0; r < 4; r++)
          op[(size_t)(mrow + r) * NPOS + n] = f2bf(acc[i][j][r] + bv[i][r]);
      }
    }
  } else {
#pragma unroll
    for (int i = 0; i < 4; i++) {
      int c0 = m0 + wm * 64 + i * 16 + (lane >> 4) * 4;
      int h = c0 >> 5, d0 = c0 & 31;
      short* op = outp + (size_t)(b * NH + h) * NPOS * HDIM;
#pragma unroll
      for (int j = 0; j < 4; j++) {
        int n = n0 + wn * 64 + j * 16 + (lane & 15);
        short4v s;
#pragma unroll
        for (int r = 0; r < 4; r++) s[r] = f2bf(acc[i][j][r] + bv[i][r]);
        *(short4v*)&op[(size_t)n * HDIM + d0] = s;
      }
    }
  }
}

// ---------------------------------------------------------------------------
// Kernel 2: flash cross-attention with block-cooperative LDS staging.
// Block = 4 waves, 64 queries (wave w owns 16). 36 K-tiles of 64 keys.
// K[64][32] and V[32][64] tiles staged cooperatively (coalesced 16B/thread),
// double-buffered, ONE barrier/iter; next-tile loads issued before compute
// (T14 split) so L2 latency hides under QK+exp+PV.
// Fixed-max softmax: P = 2^(S'-32); scale cancels in O/l. No in-loop shuffles.
// LDS pitches: K 40, V 72 (hand-verified conflict-free for all b128 patterns);
// P repack uses r2's proven zero-conflict Pl[16][68].
// ---------------------------------------------------------------------------
__global__ __launch_bounds__(256) void attn_kernel(
    const short* Q1t, const short* K1t, const short* V1,
    const short* Q2t, const short* K2t, const short* V2,
    short* O1, short* O2) {
  // bijective XCD swizzle: 1152 blocks = 8 XCDs x 144 (= 4 (z,h) combos x 36)
  const int id = blockIdx.x;
  const int nid = (id & 7) * 144 + (id >> 3);
  const int wt = nid % 36;            // q-tile index (64 rows)
  const int rest = nid / 36;          // 0..31
  const int h = rest & 7;
  const int z = rest >> 3;            // 0..3
  const int b = z >> 1, dir = z & 1;

  const short* Qp = (dir ? Q2t : Q1t) + (size_t)(b * NH + h) * NPOS * HDIM;
  const short* Kp = (dir ? K1t : K2t) + (size_t)(b * NH + h) * NPOS * HDIM;
  const short* Vp = (dir ? V1 : V2) + (size_t)b * HIDC * NPOS + (size_t)h * HDIM * NPOS;
  short*       Op = (dir ? O2 : O1) + (size_t)b * HIDC * NPOS + (size_t)h * HDIM * NPOS;

  __shared__ __attribute__((aligned(16))) short Kl[2][64][40];
  __shared__ __attribute__((aligned(16))) short Vl[2][32][72];
  __shared__ __attribute__((aligned(16))) short Pl[4][16][68];

  const int tid = threadIdx.x;
  const int lane = tid & 63;
  const int w = tid >> 6;
  const int q = lane & 15, g = lane >> 4;
  const int q0 = wt * 64 + w * 16;

  // Q as B-frag (Q^T[n][d]: lane q reads 8 consecutive d at d0=g*8)
  const short8 qf = *(const short8*)(Qp + (size_t)(q0 + q) * HDIM + g * 8);

  // staging geometry (16B per thread, coalesced)
  const int krow = tid >> 2, kcol = (tid & 3) * 8;   // K tile [64][32]
  const int vrow = tid >> 3, vcol = (tid & 7) * 8;   // V tile [32][64]
  const short* Vrow = Vp + (size_t)vrow * NPOS;

  // prologue: stage tile 0 into buf 0
  {
    short8 sk = *(const short8*)(Kp + tid * 8);           // K tile fully contiguous
    short8 sv = *(const short8*)(Vrow + vcol);
    *(short8*)&Kl[0][krow][kcol] = sk;
    *(short8*)&Vl[0][vrow][vcol] = sv;
  }
  __syncthreads();

  const f32x4 fz = {0.f, 0.f, 0.f, 0.f};
  f32x4 acco0 = fz, acco1 = fz;       // O^T: rows d = g*4+r (+16), col q
  f32x4 lrv = fz;                     // lane-local partial l sums
  int cur = 0;

  for (int t = 0; t < 36; t++) {
    // issue next-tile loads early (hide L2 latency under compute)
    const int ktn = (t < 35) ? (t + 1) * 64 : 0;
    short8 sk = *(const short8*)(Kp + ktn * 32 + tid * 8);
    short8 sv = *(const short8*)(Vrow + ktn + vcol);

    // frags from LDS
    short8 kfr[4], vfr[2][2];
#pragma unroll
    for (int f = 0; f < 4; f++)
      kfr[f] = *(const short8*)&Kl[cur][f * 16 + q][g * 8];
#pragma unroll
    for (int dc = 0; dc < 2; dc++)
#pragma unroll
      for (int mc = 0; mc < 2; mc++)
        vfr[dc][mc] = *(const short8*)&Vl[cur][dc * 16 + q][mc * 32 + g * 8];

    // S^T = K . Q^T
    f32x4 sT[4];
#pragma unroll
    for (int f = 0; f < 4; f++)
      sT[f] = __builtin_amdgcn_mfma_f32_16x16x32_bf16(kfr[f], qf, fz, 0, 0, 0);

    // fixed-max exponential, lane-local l accumulation
#pragma unroll
    for (int f = 0; f < 4; f++)
#pragma unroll
      for (int r = 0; r < 4; r++) {
        float p = exp2_asm(sT[f][r] - 32.0f);
        sT[f][r] = p;
        lrv[r] += p;
      }

    // pack P -> per-wave LDS row q (r2's zero-conflict layout), re-read as B-frag
#pragma unroll
    for (int f = 0; f < 4; f++) {
      uint2v pk;
      pk[0] = pkbf(sT[f][0], sT[f][1]);
      pk[1] = pkbf(sT[f][2], sT[f][3]);
      *(uint2v*)&Pl[w][q][f * 16 + g * 4] = pk;
    }
    short8 pb0 = *(const short8*)&Pl[w][q][g * 8];
    short8 pb1 = *(const short8*)&Pl[w][q][32 + g * 8];
    acco0 = __builtin_amdgcn_mfma_f32_16x16x32_bf16(vfr[0][0], pb0, acco0, 0, 0, 0);
    acco0 = __builtin_amdgcn_mfma_f32_16x16x32_bf16(vfr[0][1], pb1, acco0, 0, 0, 0);
    acco1 = __builtin_amdgcn_mfma_f32_16x16x32_bf16(vfr[1][0], pb0, acco1, 0, 0, 0);
    acco1 = __builtin_amdgcn_mfma_f32_16x16x32_bf16(vfr[1][1], pb1, acco1, 0, 0, 0);

    // write next tile into the other buffer; single barrier
    *(short8*)&Kl[cur ^ 1][krow][kcol] = sk;
    *(short8*)&Vl[cur ^ 1][vrow][vcol] = sv;
    __syncthreads();
    cur ^= 1;
  }

  float lrun = lrv[0] + lrv[1] + lrv[2] + lrv[3];
  lrun += __shfl_xor(lrun, 16);
  lrun += __shfl_xor(lrun, 32);
  const float rl = 1.0f / lrun;
#pragma unroll
  for (int r = 0; r < 4; r++) {
    Op[(size_t)(g * 4 + r) * NPOS + q0 + q] = f2bf(acco0[r] * rl);
    Op[(size_t)(16 + g * 4 + r) * NPOS + q0 + q] = f2bf(acco1[r] * rl);
  }
}

// ---------------------------------------------------------------------------
// Kernel 3: output projections (unchanged from round 3).
// ---------------------------------------------------------------------------
__global__ __launch_bounds__(256) void outproj_kernel(
    const float* Wo1, const float* bo1, const float* Wo2, const float* bo2,
    const short* O1, const short* O2, float* out) {
  const int nblk = blockIdx.x, mblk = blockIdx.y, z = blockIdx.z;
  const int b = z >> 1, dir = z & 1;
  const float* Wp = dir ? Wo2 : Wo1;
  const float* bp = dir ? bo2 : bo1;
  const short* Xp = (dir ? O2 : O1) + (size_t)b * HIDC * NPOS;
  float* op = out + (size_t)dir * BI * HIDC * NPOS + (size_t)b * HIDC * NPOS;
  const int K = 256;

  __shared__ __attribute__((aligned(16))) short Wl[128][72];
  __shared__ __attribute__((aligned(16))) short Xl[128][72];

  const int tid = threadIdx.x;
  const int lane = tid & 63;
  const int w = tid >> 6;
  const int wm = w >> 1, wn = w & 1;
  const int m0 = mblk * 128, n0 = nblk * 128;

  f32x4 acc[4][4];
  for (int i = 0; i < 4; i++)
    for (int j = 0; j < 4; j++)
      acc[i][j] = (f32x4){0.f, 0.f, 0.f, 0.f};

  for (int kt = 0; kt < K; kt += 64) {
    for (int idx = tid; idx < 128 * 16; idx += 256) {
      int row = idx >> 4, q = (idx & 15) * 4;
      const float4v wv = *(const float4v*)(Wp + (size_t)(m0 + row) * K + kt + q);
      short4v s;
      s[0] = f2bf(wv[0]); s[1] = f2bf(wv[1]); s[2] = f2bf(wv[2]); s[3] = f2bf(wv[3]);
      *(short4v*)&Wl[row][q] = s;
    }
    for (int idx = tid; idx < 2048; idx += 256) {
      int n = idx & 127, kq = (idx >> 7) * 4;
      const short* xb = Xp + (size_t)(kt + kq) * NPOS + n0 + n;
      short4v s;
      s[0] = xb[0]; s[1] = xb[NPOS]; s[2] = xb[2 * NPOS]; s[3] = xb[3 * NPOS];
      *(short4v*)&Xl[n][kq] = s;
    }
    __syncthreads();
#pragma unroll
    for (int kk = 0; kk < 2; kk++) {
      short8 af[4], bfr[4];
#pragma unroll
      for (int f = 0; f < 4; f++)
        af[f] = *(const short8*)&Wl[wm * 64 + f * 16 + (lane & 15)][kk * 32 + (lane >> 4) * 8];
#pragma unroll
      for (int f = 0; f < 4; f++)
        bfr[f] = *(const short8*)&Xl[wn * 64 + f * 16 + (lane & 15)][kk * 32 + (lane >> 4) * 8];
#pragma unroll
      for (int i = 0; i < 4; i++)
#pragma unroll
        for (int j = 0; j < 4; j++)
          acc[i][j] = __builtin_amdgcn_mfma_f32_16x16x32_bf16(af[i], bfr[j], acc[i][j], 0, 0, 0);
    }
    __syncthreads();
  }

#pragma unroll
  for (int i = 0; i < 4; i++) {
    int mrow = m0 + wm * 64 + i * 16 + (lane >> 4) * 4;
#pragma unroll
    for (int r = 0; r < 4; r++) {
      float bb = bp[mrow + r];
#pragma unroll
      for (int j = 0; j < 4; j++) {
        int n = n0 + wn * 64 + j * 16 + (lane & 15);
        op[(size_t)(mrow + r) * NPOS + n] = acc[i][j][r] + bb;
      }
    }
  }
}

// ---------------------------------------------------------------------------
extern "C" void kernel_launch(void* const* d_in, const int* in_sizes, int n_in,
                              void* d_out, int out_size, void* d_ws, size_t ws_size,
                              hipStream_t stream) {
  const float* m1 = (const float*)d_in[0];
  const float* m2 = (const float*)d_in[1];

  const size_t SZ = (size_t)BI * HIDC * NPOS;
  short* ws = (short*)d_ws;
  short* Q1t = ws + 0 * SZ;
  short* K1t = ws + 1 * SZ;
  short* V1  = ws + 2 * SZ;
  short* Q2t = ws + 3 * SZ;
  short* K2t = ws + 4 * SZ;
  short* V2  = ws + 5 * SZ;
  short* O1  = ws + 6 * SZ;
  short* O2  = ws + 7 * SZ;

  ProjArgs P;
  P.W[0] = (const float*)d_in[2];  P.bias[0] = (const float*)d_in[3];
  P.W[1] = (const float*)d_in[4];  P.bias[1] = (const float*)d_in[5];
  P.W[2] = (const float*)d_in[6];  P.bias[2] = (const float*)d_in[7];
  P.W[3] = (const float*)d_in[8];  P.bias[3] = (const float*)d_in[9];
  P.W[4] = (const float*)d_in[10]; P.bias[4] = (const float*)d_in[11];
  P.W[5] = (const float*)d_in[12]; P.bias[5] = (const float*)d_in[13];
  P.X1 = m1; P.X2 = m2;
  P.out[0] = Q1t; P.out[1] = K1t; P.out[2] = V1;
  P.out[3] = Q2t; P.out[4] = K2t; P.out[5] = V2;

  hipLaunchKernelGGL(proj_kernel, dim3(18, 2, 12), dim3(256), 0, stream, P);
  hipLaunchKernelGGL(attn_kernel, dim3(1152), dim3(256), 0, stream,
                     Q1t, K1t, V1, Q2t, K2t, V2, O1, O2);
  hipLaunchKernelGGL(outproj_kernel, dim3(18, 2, 4), dim3(256), 0, stream,
                     (const float*)d_in[14], (const float*)d_in[15],
                     (const float*)d_in[16], (const float*)d_in[17],
                     O1, O2, (float*)d_out);
}

// Round 5
// 92.903 us; speedup vs baseline: 2.4627x; 1.5382x over previous
//
#include <hip/hip_runtime.h>
#include <hip/hip_bf16.h>

#define BI 2
#define NPOS 2304
#define HIDC 256
#define NH 8
#define HDIM 32
// scale folded into Wq/bq: S' = S_raw * SCALE * log2(e), so P = 2^(S' - 32)
#define QSCALE (0.17677669529663687f * 1.4426950408889634f)

typedef __attribute__((ext_vector_type(8))) short short8;
typedef __attribute__((ext_vector_type(4))) short short4v;
typedef __attribute__((ext_vector_type(4))) float f32x4;
typedef __attribute__((ext_vector_type(4))) float float4v;
typedef __attribute__((ext_vector_type(2))) unsigned uint2v;

__device__ inline short f2bf(float f) {
  union { float f; unsigned u; } v; v.f = f;
  unsigned u = v.u;
  unsigned r = (u + 0x7FFFu + ((u >> 16) & 1u)) >> 16;
  return (short)r;
}

__device__ inline float exp2_asm(float x) {
  float r; asm("v_exp_f32 %0, %1" : "=v"(r) : "v"(x)); return r;
}

__device__ inline unsigned pkbf(float a, float b) {
  __hip_bfloat162 h = __float22bfloat162_rn(make_float2(a, b));
  union { __hip_bfloat162 h; unsigned u; } cv; cv.h = h;
  return cv.u;
}

// ---------------------------------------------------------------------------
// Kernel A: transpose-convert X f32 [b][C][N] -> Xt bf16 [b][N][C].
// 64x64 tiles through LDS. grid (36, 24): y<8 -> modal1 (C=256), else modal2.
// ---------------------------------------------------------------------------
__global__ __launch_bounds__(256) void convert_x(const float* X1, const float* X2,
                                                 short* X1t, short* X2t) {
  int nb = blockIdx.x, y = blockIdx.y;
  const float* X; short* Xt; int C, cb;
  if (y < 8) {
    int b = y >> 2; cb = y & 3; C = 256;
    X = X1 + (size_t)b * 256 * NPOS; Xt = X1t + (size_t)b * NPOS * 256;
  } else {
    int y2 = y - 8; int b = y2 >> 3; cb = y2 & 7; C = 512;
    X = X2 + (size_t)b * 512 * NPOS; Xt = X2t + (size_t)b * NPOS * 512;
  }
  const int c0 = cb * 64, n0 = nb * 64;
  __shared__ short T[64][68];
  const int tid = threadIdx.x;
  const int col4 = (tid & 15) * 4, rowb = tid >> 4;
#pragma unroll
  for (int p = 0; p < 4; p++) {
    int row = p * 16 + rowb;
    float4v v = *(const float4v*)(X + (size_t)(c0 + row) * NPOS + n0 + col4);
    T[col4 + 0][row] = f2bf(v[0]);
    T[col4 + 1][row] = f2bf(v[1]);
    T[col4 + 2][row] = f2bf(v[2]);
    T[col4 + 3][row] = f2bf(v[3]);
  }
  __syncthreads();
#pragma unroll
  for (int p = 0; p < 2; p++) {
    int n = p * 32 + (tid >> 3), c8 = (tid & 7) * 8;
    short8 s = *(const short8*)&T[n][c8];
    *(short8*)(Xt + (size_t)(n0 + n) * C + c0 + c8) = s;
  }
}

// ---------------------------------------------------------------------------
// Kernel B: convert weights f32 -> bf16 (stacked; QSCALE folded into Wq).
// ---------------------------------------------------------------------------
struct CvtWArgs {
  const float* src[8];
  short* dst[8];
  int nelem[8];
  float scale[8];
};

__global__ __launch_bounds__(256) void convert_w(CvtWArgs A) {
  const int seg = blockIdx.y;
  const int idx = (blockIdx.x * 256 + threadIdx.x) * 4;
  if (idx >= A.nelem[seg]) return;
  const float sc = A.scale[seg];
  const float4v v = *(const float4v*)(A.src[seg] + idx);
  short4v s;
  s[0] = f2bf(v[0] * sc); s[1] = f2bf(v[1] * sc);
  s[2] = f2bf(v[2] * sc); s[3] = f2bf(v[3] * sc);
  *(short4v*)(A.dst[seg] + idx) = s;
}

// ---------------------------------------------------------------------------
// Kernel C: QKV projection GEMM, pure bf16, both operands K-major.
// C[768][2304] = Wc[768][K] . Xt[2304][K]^T per (batch, modal).
// Tile 64m x 128n, BK=64, 4 waves (wave w owns n-slice w*32), reg-staged
// with early-issue, single-buffer 2-barrier loop.
// mblk 0-3 -> Q rows, 4-7 -> K rows, 8-11 -> V rows.
// Q,K scatter to [b*8+h][n][d]; V natural [b][256][n].
// ---------------------------------------------------------------------------
__global__ __launch_bounds__(256) void proj_gemm(
    const short* Wc1, const short* Wc2, const short* X1t, const short* X2t,
    const float* bq1, const float* bk1, const float* bv1,
    const float* bq2, const float* bk2, const float* bv2,
    short* Q1t, short* K1t, short* V1, short* Q2t, short* K2t, short* V2) {
  const int nblk = blockIdx.x;   // 0..17
  const int mblk = blockIdx.y;   // 0..11
  const int z = blockIdx.z;      // 0..3
  const int b = z >> 1, modal = z & 1;
  const int K = modal ? 512 : 256;
  const short* Wp = modal ? Wc2 : Wc1;
  const short* Xp = (modal ? X2t : X1t) + (size_t)b * NPOS * K;
  const int m0 = mblk * 64, n0 = nblk * 128;
  const int seg = mblk >> 2;     // 0 Q, 1 K, 2 V

  __shared__ __attribute__((aligned(16))) short Al[64][72];
  __shared__ __attribute__((aligned(16))) short Bl[128][72];

  const int tid = threadIdx.x;
  const int lane = tid & 63;
  const int w = tid >> 6;
  const int q = lane & 15, g = lane >> 4;
  const int srow = tid >> 3, scol = (tid & 7) * 8;

  short8 ra[2], rb[4];
  auto loadt = [&](int kt) {
    ra[0] = *(const short8*)(Wp + (size_t)(m0 + srow) * K + kt + scol);
    ra[1] = *(const short8*)(Wp + (size_t)(m0 + 32 + srow) * K + kt + scol);
#pragma unroll
    for (int u = 0; u < 4; u++)
      rb[u] = *(const short8*)(Xp + (size_t)(n0 + u * 32 + srow) * K + kt + scol);
  };

  loadt(0);
  f32x4 acc[4][2];
#pragma unroll
  for (int i = 0; i < 4; i++)
#pragma unroll
    for (int j = 0; j < 2; j++)
      acc[i][j] = (f32x4){0.f, 0.f, 0.f, 0.f};

  const int NT = K / 64;
  for (int t = 0; t < NT; t++) {
    *(short8*)&Al[srow][scol] = ra[0];
    *(short8*)&Al[32 + srow][scol] = ra[1];
#pragma unroll
    for (int u = 0; u < 4; u++)
      *(short8*)&Bl[u * 32 + srow][scol] = rb[u];
    __syncthreads();
    if (t + 1 < NT) loadt((t + 1) * 64);
#pragma unroll
    for (int kk = 0; kk < 2; kk++) {
      short8 af[4], bfj[2];
#pragma unroll
      for (int i = 0; i < 4; i++)
        af[i] = *(const short8*)&Al[i * 16 + q][kk * 32 + g * 8];
#pragma unroll
      for (int j = 0; j < 2; j++)
        bfj[j] = *(const short8*)&Bl[w * 32 + j * 16 + q][kk * 32 + g * 8];
#pragma unroll
      for (int i = 0; i < 4; i++)
#pragma unroll
        for (int j = 0; j < 2; j++)
          acc[i][j] = __builtin_amdgcn_mfma_f32_16x16x32_bf16(af[i], bfj[j], acc[i][j], 0, 0, 0);
    }
    __syncthreads();
  }

  const float* bp = (seg == 0) ? (modal ? bq2 : bq1)
                  : (seg == 1) ? (modal ? bk2 : bk1)
                               : (modal ? bv2 : bv1);
  const float bscale = (seg == 0) ? (float)QSCALE : 1.0f;

  if (seg < 2) {
    short* outp = (seg == 0) ? (modal ? Q2t : Q1t) : (modal ? K2t : K1t);
#pragma unroll
    for (int i = 0; i < 4; i++) {
      int c0 = (m0 & 255) + i * 16 + g * 4;  // 4 consecutive d, same head
      int h = c0 >> 5, d0 = c0 & 31;
      short* op = outp + (size_t)(b * NH + h) * NPOS * HDIM;
      float bb[4];
#pragma unroll
      for (int r = 0; r < 4; r++) bb[r] = bp[c0 + r] * bscale;
#pragma unroll
      for (int j = 0; j < 2; j++) {
        int n = n0 + w * 32 + j * 16 + q;
        short4v s;
#pragma unroll
        for (int r = 0; r < 4; r++) s[r] = f2bf(acc[i][j][r] + bb[r]);
        *(short4v*)&op[(size_t)n * HDIM + d0] = s;
      }
    }
  } else {
    short* outp = (modal ? V2 : V1) + (size_t)b * HIDC * NPOS;
#pragma unroll
    for (int i = 0; i < 4; i++) {
      int c0 = (m0 & 255) + i * 16 + g * 4;
#pragma unroll
      for (int j = 0; j < 2; j++) {
        int n = n0 + w * 32 + j * 16 + q;
#pragma unroll
        for (int r = 0; r < 4; r++)
          outp[(size_t)(c0 + r) * NPOS + n] = f2bf(acc[i][j][r] + bp[c0 + r]);
      }
    }
  }
}

// ---------------------------------------------------------------------------
// Kernel D: flash cross-attention (r4 structure; only O store layout changed
// to n-major [b][n][256] so outproj becomes a K-major bf16 GEMM).
// ---------------------------------------------------------------------------
__global__ __launch_bounds__(256) void attn_kernel(
    const short* Q1t, const short* K1t, const short* V1,
    const short* Q2t, const short* K2t, const short* V2,
    short* On1, short* On2) {
  // bijective XCD swizzle: 1152 blocks = 8 XCDs x 144 (= 4 (z,h) combos x 36)
  const int id = blockIdx.x;
  const int nid = (id & 7) * 144 + (id >> 3);
  const int wt = nid % 36;
  const int rest = nid / 36;
  const int h = rest & 7;
  const int z = rest >> 3;
  const int b = z >> 1, dir = z & 1;

  const short* Qp = (dir ? Q2t : Q1t) + (size_t)(b * NH + h) * NPOS * HDIM;
  const short* Kp = (dir ? K1t : K2t) + (size_t)(b * NH + h) * NPOS * HDIM;
  const short* Vp = (dir ? V1 : V2) + (size_t)b * HIDC * NPOS + (size_t)h * HDIM * NPOS;
  short*      Onp = (dir ? On2 : On1) + (size_t)b * NPOS * HIDC;

  __shared__ __attribute__((aligned(16))) short Kl[2][64][40];
  __shared__ __attribute__((aligned(16))) short Vl[2][32][72];
  __shared__ __attribute__((aligned(16))) short Pl[4][16][68];

  const int tid = threadIdx.x;
  const int lane = tid & 63;
  const int w = tid >> 6;
  const int q = lane & 15, g = lane >> 4;
  const int q0 = wt * 64 + w * 16;

  const short8 qf = *(const short8*)(Qp + (size_t)(q0 + q) * HDIM + g * 8);

  const int krow = tid >> 2, kcol = (tid & 3) * 8;
  const int vrow = tid >> 3, vcol = (tid & 7) * 8;
  const short* Vrow = Vp + (size_t)vrow * NPOS;

  {
    short8 sk = *(const short8*)(Kp + tid * 8);
    short8 sv = *(const short8*)(Vrow + vcol);
    *(short8*)&Kl[0][krow][kcol] = sk;
    *(short8*)&Vl[0][vrow][vcol] = sv;
  }
  __syncthreads();

  const f32x4 fz = {0.f, 0.f, 0.f, 0.f};
  f32x4 acco0 = fz, acco1 = fz;
  f32x4 lrv = fz;
  int cur = 0;

  for (int t = 0; t < 36; t++) {
    const int ktn = (t < 35) ? (t + 1) * 64 : 0;
    short8 sk = *(const short8*)(Kp + ktn * 32 + tid * 8);
    short8 sv = *(const short8*)(Vrow + ktn + vcol);

    short8 kfr[4], vfr[2][2];
#pragma unroll
    for (int f = 0; f < 4; f++)
      kfr[f] = *(const short8*)&Kl[cur][f * 16 + q][g * 8];
#pragma unroll
    for (int dc = 0; dc < 2; dc++)
#pragma unroll
      for (int mc = 0; mc < 2; mc++)
        vfr[dc][mc] = *(const short8*)&Vl[cur][dc * 16 + q][mc * 32 + g * 8];

    f32x4 sT[4];
#pragma unroll
    for (int f = 0; f < 4; f++)
      sT[f] = __builtin_amdgcn_mfma_f32_16x16x32_bf16(kfr[f], qf, fz, 0, 0, 0);

#pragma unroll
    for (int f = 0; f < 4; f++)
#pragma unroll
      for (int r = 0; r < 4; r++) {
        float p = exp2_asm(sT[f][r] - 32.0f);
        sT[f][r] = p;
        lrv[r] += p;
      }

#pragma unroll
    for (int f = 0; f < 4; f++) {
      uint2v pk;
      pk[0] = pkbf(sT[f][0], sT[f][1]);
      pk[1] = pkbf(sT[f][2], sT[f][3]);
      *(uint2v*)&Pl[w][q][f * 16 + g * 4] = pk;
    }
    short8 pb0 = *(const short8*)&Pl[w][q][g * 8];
    short8 pb1 = *(const short8*)&Pl[w][q][32 + g * 8];
    acco0 = __builtin_amdgcn_mfma_f32_16x16x32_bf16(vfr[0][0], pb0, acco0, 0, 0, 0);
    acco0 = __builtin_amdgcn_mfma_f32_16x16x32_bf16(vfr[0][1], pb1, acco0, 0, 0, 0);
    acco1 = __builtin_amdgcn_mfma_f32_16x16x32_bf16(vfr[1][0], pb0, acco1, 0, 0, 0);
    acco1 = __builtin_amdgcn_mfma_f32_16x16x32_bf16(vfr[1][1], pb1, acco1, 0, 0, 0);

    *(short8*)&Kl[cur ^ 1][krow][kcol] = sk;
    *(short8*)&Vl[cur ^ 1][vrow][vcol] = sv;
    __syncthreads();
    cur ^= 1;
  }

  float lrun = lrv[0] + lrv[1] + lrv[2] + lrv[3];
  lrun += __shfl_xor(lrun, 16);
  lrun += __shfl_xor(lrun, 32);
  const float rl = 1.0f / lrun;
  // O n-major: [q0+q][h*32 + dc*16 + g*4 + r]
#pragma unroll
  for (int dc = 0; dc < 2; dc++) {
    short4v s4;
#pragma unroll
    for (int r = 0; r < 4; r++) s4[r] = f2bf((dc ? acco1[r] : acco0[r]) * rl);
    *(short4v*)&Onp[(size_t)(q0 + q) * HIDC + h * HDIM + dc * 16 + g * 4] = s4;
  }
}

// ---------------------------------------------------------------------------
// Kernel E: output projection GEMM, pure bf16 K-major (same structure as
// proj_gemm). out[o][n] f32 = Wo[256][256] . On[2304][256]^T + bo.
// ---------------------------------------------------------------------------
__global__ __launch_bounds__(256) void outproj_kernel(
    const short* Wo1b, const short* Wo2b, const float* bo1, const float* bo2,
    const short* On1, const short* On2, float* out) {
  const int nblk = blockIdx.x;   // 0..17
  const int mblk = blockIdx.y;   // 0..3
  const int z = blockIdx.z;      // 0..3
  const int dir = z >> 1, b = z & 1;
  const short* Wp = dir ? Wo2b : Wo1b;
  const float* bp = dir ? bo2 : bo1;
  const short* Xp = (dir ? On2 : On1) + (size_t)b * NPOS * HIDC;
  float* op = out + (size_t)dir * BI * HIDC * NPOS + (size_t)b * HIDC * NPOS;
  const int m0 = mblk * 64, n0 = nblk * 128;

  __shared__ __attribute__((aligned(16))) short Al[64][72];
  __shared__ __attribute__((aligned(16))) short Bl[128][72];

  const int tid = threadIdx.x;
  const int lane = tid & 63;
  const int w = tid >> 6;
  const int q = lane & 15, g = lane >> 4;
  const int srow = tid >> 3, scol = (tid & 7) * 8;

  short8 ra[2], rb[4];
  auto loadt = [&](int kt) {
    ra[0] = *(const short8*)(Wp + (size_t)(m0 + srow) * HIDC + kt + scol);
    ra[1] = *(const short8*)(Wp + (size_t)(m0 + 32 + srow) * HIDC + kt + scol);
#pragma unroll
    for (int u = 0; u < 4; u++)
      rb[u] = *(const short8*)(Xp + (size_t)(n0 + u * 32 + srow) * HIDC + kt + scol);
  };

  loadt(0);
  f32x4 acc[4][2];
#pragma unroll
  for (int i = 0; i < 4; i++)
#pragma unroll
    for (int j = 0; j < 2; j++)
      acc[i][j] = (f32x4){0.f, 0.f, 0.f, 0.f};

  for (int t = 0; t < 4; t++) {
    *(short8*)&Al[srow][scol] = ra[0];
    *(short8*)&Al[32 + srow][scol] = ra[1];
#pragma unroll
    for (int u = 0; u < 4; u++)
      *(short8*)&Bl[u * 32 + srow][scol] = rb[u];
    __syncthreads();
    if (t + 1 < 4) loadt((t + 1) * 64);
#pragma unroll
    for (int kk = 0; kk < 2; kk++) {
      short8 af[4], bfj[2];
#pragma unroll
      for (int i = 0; i < 4; i++)
        af[i] = *(const short8*)&Al[i * 16 + q][kk * 32 + g * 8];
#pragma unroll
      for (int j = 0; j < 2; j++)
        bfj[j] = *(const short8*)&Bl[w * 32 + j * 16 + q][kk * 32 + g * 8];
#pragma unroll
      for (int i = 0; i < 4; i++)
#pragma unroll
        for (int j = 0; j < 2; j++)
          acc[i][j] = __builtin_amdgcn_mfma_f32_16x16x32_bf16(af[i], bfj[j], acc[i][j], 0, 0, 0);
    }
    __syncthreads();
  }

#pragma unroll
  for (int i = 0; i < 4; i++) {
    int c0 = m0 + i * 16 + g * 4;
#pragma unroll
    for (int r = 0; r < 4; r++) {
      float bb = bp[c0 + r];
#pragma unroll
      for (int j = 0; j < 2; j++) {
        int n = n0 + w * 32 + j * 16 + q;
        op[(size_t)(c0 + r) * NPOS + n] = acc[i][j][r] + bb;
      }
    }
  }
}

// ---------------------------------------------------------------------------
extern "C" void kernel_launch(void* const* d_in, const int* in_sizes, int n_in,
                              void* d_out, int out_size, void* d_ws, size_t ws_size,
                              hipStream_t stream) {
  const float* m1 = (const float*)d_in[0];
  const float* m2 = (const float*)d_in[1];

  const size_t SZ = (size_t)BI * HIDC * NPOS;  // 1,179,648 elements
  short* ws = (short*)d_ws;
  short* Q1t = ws + 0 * SZ;
  short* K1t = ws + 1 * SZ;
  short* V1  = ws + 2 * SZ;
  short* Q2t = ws + 3 * SZ;
  short* K2t = ws + 4 * SZ;
  short* V2  = ws + 5 * SZ;
  short* X1t = ws + 6 * SZ;          // [2][2304][256]  (1 SZ)
  short* X2t = ws + 7 * SZ;          // [2][2304][512]  (2 SZ)
  short* On1 = X1t;                  // alias: X dead before attn writes O
  short* On2 = ws + 9 * SZ;          // [2][2304][256]  (1 SZ)
  short* Wc1 = ws + 10 * SZ;         // 768*256
  short* Wc2 = Wc1 + 768 * 256;      // 768*512
  short* Wo1b = Wc2 + 768 * 512;     // 256*256
  short* Wo2b = Wo1b + 256 * 256;

  // A: transpose-convert X
  hipLaunchKernelGGL(convert_x, dim3(36, 24), dim3(256), 0, stream, m1, m2, X1t, X2t);

  // B: convert weights
  CvtWArgs CW;
  CW.src[0] = (const float*)d_in[2];  CW.dst[0] = Wc1;             CW.nelem[0] = 65536;  CW.scale[0] = (float)QSCALE; // Wq1
  CW.src[1] = (const float*)d_in[4];  CW.dst[1] = Wc1 + 65536;     CW.nelem[1] = 65536;  CW.scale[1] = 1.f;           // Wk1
  CW.src[2] = (const float*)d_in[6];  CW.dst[2] = Wc1 + 131072;    CW.nelem[2] = 65536;  CW.scale[2] = 1.f;           // Wv1
  CW.src[3] = (const float*)d_in[8];  CW.dst[3] = Wc2;             CW.nelem[3] = 131072; CW.scale[3] = (float)QSCALE; // Wq2
  CW.src[4] = (const float*)d_in[10]; CW.dst[4] = Wc2 + 131072;    CW.nelem[4] = 131072; CW.scale[4] = 1.f;           // Wk2
  CW.src[5] = (const float*)d_in[12]; CW.dst[5] = Wc2 + 262144;    CW.nelem[5] = 131072; CW.scale[5] = 1.f;           // Wv2
  CW.src[6] = (const float*)d_in[14]; CW.dst[6] = Wo1b;            CW.nelem[6] = 65536;  CW.scale[6] = 1.f;           // Wo1
  CW.src[7] = (const float*)d_in[16]; CW.dst[7] = Wo2b;            CW.nelem[7] = 65536;  CW.scale[7] = 1.f;           // Wo2
  hipLaunchKernelGGL(convert_w, dim3(128, 8), dim3(256), 0, stream, CW);

  // C: QKV projection GEMM
  hipLaunchKernelGGL(proj_gemm, dim3(18, 12, 4), dim3(256), 0, stream,
                     Wc1, Wc2, X1t, X2t,
                     (const float*)d_in[3], (const float*)d_in[5], (const float*)d_in[7],
                     (const float*)d_in[9], (const float*)d_in[11], (const float*)d_in[13],
                     Q1t, K1t, V1, Q2t, K2t, V2);

  // D: attention
  hipLaunchKernelGGL(attn_kernel, dim3(1152), dim3(256), 0, stream,
                     Q1t, K1t, V1, Q2t, K2t, V2, On1, On2);

  // E: output projection GEMM
  hipLaunchKernelGGL(outproj_kernel, dim3(18, 4, 4), dim3(256), 0, stream,
                     Wo1b, Wo2b, (const float*)d_in[15], (const float*)d_in[17],
                     On1, On2, (float*)d_out);
}

// Round 6
// 90.424 us; speedup vs baseline: 2.5302x; 1.0274x over previous
//
#include <hip/hip_runtime.h>
#include <hip/hip_bf16.h>

#define BI 2
#define NPOS 2304
#define HIDC 256
#define NH 8
#define HDIM 32
// scale folded into Wq/bq: S' = S_raw * SCALE * log2(e); P = 2^(S' - 32) via
// MFMA C-input = -32 (fixed-max softmax: the 2^-32 scale cancels in O/l).
#define QSCALE (0.17677669529663687f * 1.4426950408889634f)

typedef __attribute__((ext_vector_type(8))) short short8;
typedef __attribute__((ext_vector_type(4))) short short4v;
typedef __attribute__((ext_vector_type(4))) float f32x4;
typedef __attribute__((ext_vector_type(4))) float float4v;
typedef __attribute__((ext_vector_type(2))) unsigned uint2v;

__device__ inline short f2bf(float f) {
  union { float f; unsigned u; } v; v.f = f;
  unsigned u = v.u;
  unsigned r = (u + 0x7FFFu + ((u >> 16) & 1u)) >> 16;
  return (short)r;
}

__device__ inline float bf2f(short s) {
  union { unsigned u; float f; } v;
  v.u = ((unsigned)(unsigned short)s) << 16;
  return v.f;
}

__device__ inline float exp2_asm(float x) {
  float r; asm("v_exp_f32 %0, %1" : "=v"(r) : "v"(x)); return r;
}

__device__ inline unsigned pkbf(float a, float b) {
  __hip_bfloat162 h = __float22bfloat162_rn(make_float2(a, b));
  union { __hip_bfloat162 h; unsigned u; } cv; cv.h = h;
  return cv.u;
}

// ---------------------------------------------------------------------------
// Kernel A: transpose-convert X f32 [b][C][N] -> Xt bf16 [b][N][C].
// ---------------------------------------------------------------------------
__global__ __launch_bounds__(256) void convert_x(const float* X1, const float* X2,
                                                 short* X1t, short* X2t) {
  int nb = blockIdx.x, y = blockIdx.y;
  const float* X; short* Xt; int C, cb;
  if (y < 8) {
    int b = y >> 2; cb = y & 3; C = 256;
    X = X1 + (size_t)b * 256 * NPOS; Xt = X1t + (size_t)b * NPOS * 256;
  } else {
    int y2 = y - 8; int b = y2 >> 3; cb = y2 & 7; C = 512;
    X = X2 + (size_t)b * 512 * NPOS; Xt = X2t + (size_t)b * NPOS * 512;
  }
  const int c0 = cb * 64, n0 = nb * 64;
  __shared__ short T[64][68];
  const int tid = threadIdx.x;
  const int col4 = (tid & 15) * 4, rowb = tid >> 4;
#pragma unroll
  for (int p = 0; p < 4; p++) {
    int row = p * 16 + rowb;
    float4v v = *(const float4v*)(X + (size_t)(c0 + row) * NPOS + n0 + col4);
    T[col4 + 0][row] = f2bf(v[0]);
    T[col4 + 1][row] = f2bf(v[1]);
    T[col4 + 2][row] = f2bf(v[2]);
    T[col4 + 3][row] = f2bf(v[3]);
  }
  __syncthreads();
#pragma unroll
  for (int p = 0; p < 2; p++) {
    int n = p * 32 + (tid >> 3), c8 = (tid & 7) * 8;
    short8 s = *(const short8*)&T[n][c8];
    *(short8*)(Xt + (size_t)(n0 + n) * C + c0 + c8) = s;
  }
}

// ---------------------------------------------------------------------------
// Kernel B: convert weights f32 -> bf16 (stacked; QSCALE folded into Wq).
// ---------------------------------------------------------------------------
struct CvtWArgs {
  const float* src[8];
  short* dst[8];
  int nelem[8];
  float scale[8];
};

__global__ __launch_bounds__(256) void convert_w(CvtWArgs A) {
  const int seg = blockIdx.y;
  const int idx = (blockIdx.x * 256 + threadIdx.x) * 4;
  if (idx >= A.nelem[seg]) return;
  const float sc = A.scale[seg];
  const float4v v = *(const float4v*)(A.src[seg] + idx);
  short4v s;
  s[0] = f2bf(v[0] * sc); s[1] = f2bf(v[1] * sc);
  s[2] = f2bf(v[2] * sc); s[3] = f2bf(v[3] * sc);
  *(short4v*)(A.dst[seg] + idx) = s;
}

// ---------------------------------------------------------------------------
// Kernel C: QKV projection GEMM (unchanged from r5).
// ---------------------------------------------------------------------------
__global__ __launch_bounds__(256) void proj_gemm(
    const short* Wc1, const short* Wc2, const short* X1t, const short* X2t,
    const float* bq1, const float* bk1, const float* bv1,
    const float* bq2, const float* bk2, const float* bv2,
    short* Q1t, short* K1t, short* V1, short* Q2t, short* K2t, short* V2) {
  const int nblk = blockIdx.x;   // 0..17
  const int mblk = blockIdx.y;   // 0..11
  const int z = blockIdx.z;      // 0..3
  const int b = z >> 1, modal = z & 1;
  const int K = modal ? 512 : 256;
  const short* Wp = modal ? Wc2 : Wc1;
  const short* Xp = (modal ? X2t : X1t) + (size_t)b * NPOS * K;
  const int m0 = mblk * 64, n0 = nblk * 128;
  const int seg = mblk >> 2;     // 0 Q, 1 K, 2 V

  __shared__ __attribute__((aligned(16))) short Al[64][72];
  __shared__ __attribute__((aligned(16))) short Bl[128][72];

  const int tid = threadIdx.x;
  const int lane = tid & 63;
  const int w = tid >> 6;
  const int q = lane & 15, g = lane >> 4;
  const int srow = tid >> 3, scol = (tid & 7) * 8;

  short8 ra[2], rb[4];
  auto loadt = [&](int kt) {
    ra[0] = *(const short8*)(Wp + (size_t)(m0 + srow) * K + kt + scol);
    ra[1] = *(const short8*)(Wp + (size_t)(m0 + 32 + srow) * K + kt + scol);
#pragma unroll
    for (int u = 0; u < 4; u++)
      rb[u] = *(const short8*)(Xp + (size_t)(n0 + u * 32 + srow) * K + kt + scol);
  };

  loadt(0);
  f32x4 acc[4][2];
#pragma unroll
  for (int i = 0; i < 4; i++)
#pragma unroll
    for (int j = 0; j < 2; j++)
      acc[i][j] = (f32x4){0.f, 0.f, 0.f, 0.f};

  const int NT = K / 64;
  for (int t = 0; t < NT; t++) {
    *(short8*)&Al[srow][scol] = ra[0];
    *(short8*)&Al[32 + srow][scol] = ra[1];
#pragma unroll
    for (int u = 0; u < 4; u++)
      *(short8*)&Bl[u * 32 + srow][scol] = rb[u];
    __syncthreads();
    if (t + 1 < NT) loadt((t + 1) * 64);
#pragma unroll
    for (int kk = 0; kk < 2; kk++) {
      short8 af[4], bfj[2];
#pragma unroll
      for (int i = 0; i < 4; i++)
        af[i] = *(const short8*)&Al[i * 16 + q][kk * 32 + g * 8];
#pragma unroll
      for (int j = 0; j < 2; j++)
        bfj[j] = *(const short8*)&Bl[w * 32 + j * 16 + q][kk * 32 + g * 8];
#pragma unroll
      for (int i = 0; i < 4; i++)
#pragma unroll
        for (int j = 0; j < 2; j++)
          acc[i][j] = __builtin_amdgcn_mfma_f32_16x16x32_bf16(af[i], bfj[j], acc[i][j], 0, 0, 0);
    }
    __syncthreads();
  }

  const float* bp = (seg == 0) ? (modal ? bq2 : bq1)
                  : (seg == 1) ? (modal ? bk2 : bk1)
                               : (modal ? bv2 : bv1);
  const float bscale = (seg == 0) ? (float)QSCALE : 1.0f;

  if (seg < 2) {
    short* outp = (seg == 0) ? (modal ? Q2t : Q1t) : (modal ? K2t : K1t);
#pragma unroll
    for (int i = 0; i < 4; i++) {
      int c0 = (m0 & 255) + i * 16 + g * 4;
      int h = c0 >> 5, d0 = c0 & 31;
      short* op = outp + (size_t)(b * NH + h) * NPOS * HDIM;
      float bb[4];
#pragma unroll
      for (int r = 0; r < 4; r++) bb[r] = bp[c0 + r] * bscale;
#pragma unroll
      for (int j = 0; j < 2; j++) {
        int n = n0 + w * 32 + j * 16 + q;
        short4v s;
#pragma unroll
        for (int r = 0; r < 4; r++) s[r] = f2bf(acc[i][j][r] + bb[r]);
        *(short4v*)&op[(size_t)n * HDIM + d0] = s;
      }
    }
  } else {
    short* outp = (modal ? V2 : V1) + (size_t)b * HIDC * NPOS;
#pragma unroll
    for (int i = 0; i < 4; i++) {
      int c0 = (m0 & 255) + i * 16 + g * 4;
#pragma unroll
      for (int j = 0; j < 2; j++) {
        int n = n0 + w * 32 + j * 16 + q;
#pragma unroll
        for (int r = 0; r < 4; r++)
          outp[(size_t)(c0 + r) * NPOS + n] = f2bf(acc[i][j][r] + bp[c0 + r]);
      }
    }
  }
}

// ---------------------------------------------------------------------------
// Kernel D: flash cross-attention, 2-way K-split for occupancy.
// Grid 2304 = 8 XCDs x 288; block (ks,z,h,qt): 4 waves, 64 queries, 18 K-tiles
// [ks*1152, +1152). Writes UNNORMALIZED O partial (bf16, d-major) + l partial
// (f32) — fixed-max makes partials linearly additive; merge_kernel combines.
// QK^T folds the -32 via MFMA C-input.
// ---------------------------------------------------------------------------
__global__ __launch_bounds__(256) void attn_kernel(
    const short* Q1t, const short* K1t, const short* V1,
    const short* Q2t, const short* K2t, const short* V2,
    short* Opart, float* Lpart) {
  // bijective XCD swizzle: 2304 = 8 XCDs x 288 (= 4 (z,h) combos x 72)
  const int id = blockIdx.x;
  const int nid = (id & 7) * 288 + (id >> 3);
  const int sub = nid % 72;
  const int ks = sub & 1;
  const int wt = sub >> 1;            // 0..35
  const int rest = nid / 72;          // 0..31
  const int h = rest & 7;
  const int z = rest >> 3;            // 0..3
  const int b = z >> 1, dir = z & 1;

  const short* Qp = (dir ? Q2t : Q1t) + (size_t)(b * NH + h) * NPOS * HDIM;
  const short* Kp = (dir ? K1t : K2t) + (size_t)(b * NH + h) * NPOS * HDIM;
  const short* Vp = (dir ? V1 : V2) + (size_t)b * HIDC * NPOS + (size_t)h * HDIM * NPOS;

  __shared__ __attribute__((aligned(16))) short Kl[2][64][40];
  __shared__ __attribute__((aligned(16))) short Vl[2][32][72];
  __shared__ __attribute__((aligned(16))) short Pl[4][16][68];

  const int tid = threadIdx.x;
  const int lane = tid & 63;
  const int w = tid >> 6;
  const int q = lane & 15, g = lane >> 4;
  const int q0 = wt * 64 + w * 16;
  const int k0 = ks * 1152;

  const short8 qf = *(const short8*)(Qp + (size_t)(q0 + q) * HDIM + g * 8);

  const int krow = tid >> 2, kcol = (tid & 3) * 8;
  const int vrow = tid >> 3, vcol = (tid & 7) * 8;
  const short* Vrow = Vp + (size_t)vrow * NPOS;

  {
    short8 sk = *(const short8*)(Kp + k0 * 32 + tid * 8);
    short8 sv = *(const short8*)(Vrow + k0 + vcol);
    *(short8*)&Kl[0][krow][kcol] = sk;
    *(short8*)&Vl[0][vrow][vcol] = sv;
  }
  __syncthreads();

  const f32x4 mC = {-32.f, -32.f, -32.f, -32.f};  // fixed-max fold
  const f32x4 fz = {0.f, 0.f, 0.f, 0.f};
  f32x4 acco0 = fz, acco1 = fz;
  f32x4 lrv = fz;
  int cur = 0;

  for (int t = 0; t < 18; t++) {
    const int ktn = k0 + ((t < 17) ? (t + 1) * 64 : 0);
    short8 sk = *(const short8*)(Kp + ktn * 32 + tid * 8);
    short8 sv = *(const short8*)(Vrow + ktn + vcol);

    short8 kfr[4], vfr[2][2];
#pragma unroll
    for (int f = 0; f < 4; f++)
      kfr[f] = *(const short8*)&Kl[cur][f * 16 + q][g * 8];
#pragma unroll
    for (int dc = 0; dc < 2; dc++)
#pragma unroll
      for (int mc = 0; mc < 2; mc++)
        vfr[dc][mc] = *(const short8*)&Vl[cur][dc * 16 + q][mc * 32 + g * 8];

    // S' - 32 = K . Q^T + (-32)
    f32x4 sT[4];
#pragma unroll
    for (int f = 0; f < 4; f++)
      sT[f] = __builtin_amdgcn_mfma_f32_16x16x32_bf16(kfr[f], qf, mC, 0, 0, 0);

#pragma unroll
    for (int f = 0; f < 4; f++)
#pragma unroll
      for (int r = 0; r < 4; r++) {
        float p = exp2_asm(sT[f][r]);
        sT[f][r] = p;
        lrv[r] += p;
      }

#pragma unroll
    for (int f = 0; f < 4; f++) {
      uint2v pk;
      pk[0] = pkbf(sT[f][0], sT[f][1]);
      pk[1] = pkbf(sT[f][2], sT[f][3]);
      *(uint2v*)&Pl[w][q][f * 16 + g * 4] = pk;
    }
    short8 pb0 = *(const short8*)&Pl[w][q][g * 8];
    short8 pb1 = *(const short8*)&Pl[w][q][32 + g * 8];
    acco0 = __builtin_amdgcn_mfma_f32_16x16x32_bf16(vfr[0][0], pb0, acco0, 0, 0, 0);
    acco0 = __builtin_amdgcn_mfma_f32_16x16x32_bf16(vfr[0][1], pb1, acco0, 0, 0, 0);
    acco1 = __builtin_amdgcn_mfma_f32_16x16x32_bf16(vfr[1][0], pb0, acco1, 0, 0, 0);
    acco1 = __builtin_amdgcn_mfma_f32_16x16x32_bf16(vfr[1][1], pb1, acco1, 0, 0, 0);

    *(short8*)&Kl[cur ^ 1][krow][kcol] = sk;
    *(short8*)&Vl[cur ^ 1][vrow][vcol] = sv;
    __syncthreads();
    cur ^= 1;
  }

  float lrun = lrv[0] + lrv[1] + lrv[2] + lrv[3];
  lrun += __shfl_xor(lrun, 16);
  lrun += __shfl_xor(lrun, 32);

  // unnormalized partials: Opart[ks][z][h][d 32][n 2304] bf16, Lpart[ks][z][h][n]
  short* Pp = Opart + (size_t)ks * (4 * 8 * 32 * (size_t)NPOS)
                    + (size_t)(z * 8 + h) * 32 * NPOS;
#pragma unroll
  for (int r = 0; r < 4; r++) {
    Pp[(size_t)(g * 4 + r) * NPOS + q0 + q] = f2bf(acco0[r]);
    Pp[(size_t)(16 + g * 4 + r) * NPOS + q0 + q] = f2bf(acco1[r]);
  }
  if (g == 0)
    Lpart[(size_t)ks * (4 * 8 * NPOS) + (size_t)(z * 8 + h) * NPOS + q0 + q] = lrun;
}

// ---------------------------------------------------------------------------
// Kernel D2: merge K-split partials, normalize, transpose to On n-major.
// grid (36, 32): nt x (z*8+h). ~28MB traffic, memory-bound.
// ---------------------------------------------------------------------------
__global__ __launch_bounds__(256) void merge_kernel(
    const short* Opart, const float* Lpart, short* On1, short* On2) {
  const int nt = blockIdx.x;
  const int zh = blockIdx.y;
  const int z = zh >> 3, h = zh & 7;
  const int b = z >> 1, dir = z & 1;
  const int n0 = nt * 64;
  const size_t PH = (size_t)4 * 8 * 32 * NPOS;
  const short* P0 = Opart + (size_t)zh * 32 * NPOS;
  const short* P1 = P0 + PH;
  const float* L0 = Lpart + (size_t)zh * NPOS;
  const float* L1 = L0 + (size_t)4 * 8 * NPOS;
  short* On = (dir ? On2 : On1) + (size_t)b * NPOS * HIDC;

  __shared__ float rl[64];
  __shared__ short T[64][36];

  const int tid = threadIdx.x;
  if (tid < 64) rl[tid] = 1.0f / (L0[n0 + tid] + L1[n0 + tid]);
  __syncthreads();

  const int d = tid >> 3, nc = (tid & 7) * 8;
  short8 a = *(const short8*)(P0 + (size_t)d * NPOS + n0 + nc);
  short8 c = *(const short8*)(P1 + (size_t)d * NPOS + n0 + nc);
#pragma unroll
  for (int j = 0; j < 8; j++)
    T[nc + j][d] = f2bf((bf2f(a[j]) + bf2f(c[j])) * rl[nc + j]);
  __syncthreads();

  const int n = tid >> 2, c8 = (tid & 3) * 8;
  short8 o = *(const short8*)&T[n][c8];
  *(short8*)(On + (size_t)(n0 + n) * HIDC + h * HDIM + c8) = o;
}

// ---------------------------------------------------------------------------
// Kernel E: output projection GEMM (unchanged from r5).
// ---------------------------------------------------------------------------
__global__ __launch_bounds__(256) void outproj_kernel(
    const short* Wo1b, const short* Wo2b, const float* bo1, const float* bo2,
    const short* On1, const short* On2, float* out) {
  const int nblk = blockIdx.x;
  const int mblk = blockIdx.y;
  const int z = blockIdx.z;
  const int dir = z >> 1, b = z & 1;
  const short* Wp = dir ? Wo2b : Wo1b;
  const float* bp = dir ? bo2 : bo1;
  const short* Xp = (dir ? On2 : On1) + (size_t)b * NPOS * HIDC;
  float* op = out + (size_t)dir * BI * HIDC * NPOS + (size_t)b * HIDC * NPOS;
  const int m0 = mblk * 64, n0 = nblk * 128;

  __shared__ __attribute__((aligned(16))) short Al[64][72];
  __shared__ __attribute__((aligned(16))) short Bl[128][72];

  const int tid = threadIdx.x;
  const int lane = tid & 63;
  const int w = tid >> 6;
  const int q = lane & 15, g = lane >> 4;
  const int srow = tid >> 3, scol = (tid & 7) * 8;

  short8 ra[2], rb[4];
  auto loadt = [&](int kt) {
    ra[0] = *(const short8*)(Wp + (size_t)(m0 + srow) * HIDC + kt + scol);
    ra[1] = *(const short8*)(Wp + (size_t)(m0 + 32 + srow) * HIDC + kt + scol);
#pragma unroll
    for (int u = 0; u < 4; u++)
      rb[u] = *(const short8*)(Xp + (size_t)(n0 + u * 32 + srow) * HIDC + kt + scol);
  };

  loadt(0);
  f32x4 acc[4][2];
#pragma unroll
  for (int i = 0; i < 4; i++)
#pragma unroll
    for (int j = 0; j < 2; j++)
      acc[i][j] = (f32x4){0.f, 0.f, 0.f, 0.f};

  for (int t = 0; t < 4; t++) {
    *(short8*)&Al[srow][scol] = ra[0];
    *(short8*)&Al[32 + srow][scol] = ra[1];
#pragma unroll
    for (int u = 0; u < 4; u++)
      *(short8*)&Bl[u * 32 + srow][scol] = rb[u];
    __syncthreads();
    if (t + 1 < 4) loadt((t + 1) * 64);
#pragma unroll
    for (int kk = 0; kk < 2; kk++) {
      short8 af[4], bfj[2];
#pragma unroll
      for (int i = 0; i < 4; i++)
        af[i] = *(const short8*)&Al[i * 16 + q][kk * 32 + g * 8];
#pragma unroll
      for (int j = 0; j < 2; j++)
        bfj[j] = *(const short8*)&Bl[w * 32 + j * 16 + q][kk * 32 + g * 8];
#pragma unroll
      for (int i = 0; i < 4; i++)
#pragma unroll
        for (int j = 0; j < 2; j++)
          acc[i][j] = __builtin_amdgcn_mfma_f32_16x16x32_bf16(af[i], bfj[j], acc[i][j], 0, 0, 0);
    }
    __syncthreads();
  }

#pragma unroll
  for (int i = 0; i < 4; i++) {
    int c0 = m0 + i * 16 + g * 4;
#pragma unroll
    for (int r = 0; r < 4; r++) {
      float bb = bp[c0 + r];
#pragma unroll
      for (int j = 0; j < 2; j++) {
        int n = n0 + w * 32 + j * 16 + q;
        op[(size_t)(c0 + r) * NPOS + n] = acc[i][j][r] + bb;
      }
    }
  }
}

// ---------------------------------------------------------------------------
extern "C" void kernel_launch(void* const* d_in, const int* in_sizes, int n_in,
                              void* d_out, int out_size, void* d_ws, size_t ws_size,
                              hipStream_t stream) {
  const float* m1 = (const float*)d_in[0];
  const float* m2 = (const float*)d_in[1];

  const size_t SZ = (size_t)BI * HIDC * NPOS;  // 1,179,648 elements
  short* ws = (short*)d_ws;
  short* Q1t = ws + 0 * SZ;
  short* K1t = ws + 1 * SZ;
  short* V1  = ws + 2 * SZ;
  short* Q2t = ws + 3 * SZ;
  short* K2t = ws + 4 * SZ;
  short* V2  = ws + 5 * SZ;
  short* X1t = ws + 6 * SZ;              // [2][2304][256]  dead after proj_gemm
  short* X2t = ws + 7 * SZ;              // [2][2304][512]  dead after proj_gemm
  short* Opart = ws + 6 * SZ;            // [2ks][4z][8h][32d][2304n] bf16 (4 SZ, overlays X)
  float* Lpart = (float*)(ws + 10 * SZ); // [2ks][4z][8h][2304n] f32 (589,824 B)
  short* On1 = ws + 11 * SZ;
  short* On2 = ws + 12 * SZ;
  short* Wc1 = ws + 13 * SZ;             // 768*256
  short* Wc2 = Wc1 + 768 * 256;          // 768*512
  short* Wo1b = Wc2 + 768 * 512;         // 256*256
  short* Wo2b = Wo1b + 256 * 256;

  // A: transpose-convert X
  hipLaunchKernelGGL(convert_x, dim3(36, 24), dim3(256), 0, stream, m1, m2, X1t, X2t);

  // B: convert weights
  CvtWArgs CW;
  CW.src[0] = (const float*)d_in[2];  CW.dst[0] = Wc1;          CW.nelem[0] = 65536;  CW.scale[0] = (float)QSCALE;
  CW.src[1] = (const float*)d_in[4];  CW.dst[1] = Wc1 + 65536;  CW.nelem[1] = 65536;  CW.scale[1] = 1.f;
  CW.src[2] = (const float*)d_in[6];  CW.dst[2] = Wc1 + 131072; CW.nelem[2] = 65536;  CW.scale[2] = 1.f;
  CW.src[3] = (const float*)d_in[8];  CW.dst[3] = Wc2;          CW.nelem[3] = 131072; CW.scale[3] = (float)QSCALE;
  CW.src[4] = (const float*)d_in[10]; CW.dst[4] = Wc2 + 131072; CW.nelem[4] = 131072; CW.scale[4] = 1.f;
  CW.src[5] = (const float*)d_in[12]; CW.dst[5] = Wc2 + 262144; CW.nelem[5] = 131072; CW.scale[5] = 1.f;
  CW.src[6] = (const float*)d_in[14]; CW.dst[6] = Wo1b;         CW.nelem[6] = 65536;  CW.scale[6] = 1.f;
  CW.src[7] = (const float*)d_in[16]; CW.dst[7] = Wo2b;         CW.nelem[7] = 65536;  CW.scale[7] = 1.f;
  hipLaunchKernelGGL(convert_w, dim3(128, 8), dim3(256), 0, stream, CW);

  // C: QKV projection GEMM
  hipLaunchKernelGGL(proj_gemm, dim3(18, 12, 4), dim3(256), 0, stream,
                     Wc1, Wc2, X1t, X2t,
                     (const float*)d_in[3], (const float*)d_in[5], (const float*)d_in[7],
                     (const float*)d_in[9], (const float*)d_in[11], (const float*)d_in[13],
                     Q1t, K1t, V1, Q2t, K2t, V2);

  // D: attention (K-split partials)
  hipLaunchKernelGGL(attn_kernel, dim3(2304), dim3(256), 0, stream,
                     Q1t, K1t, V1, Q2t, K2t, V2, Opart, Lpart);

  // D2: merge + normalize + transpose
  hipLaunchKernelGGL(merge_kernel, dim3(36, 32), dim3(256), 0, stream,
                     Opart, Lpart, On1, On2);

  // E: output projection GEMM
  hipLaunchKernelGGL(outproj_kernel, dim3(18, 4, 4), dim3(256), 0, stream,
                     Wo1b, Wo2b, (const float*)d_in[15], (const float*)d_in[17],
                     On1, On2, (float*)d_out);
}